// Round 7
// baseline (188.733 us; speedup 1.0000x reference)
//
#include <hip/hip_runtime.h>
#include <math.h>
#include <stdint.h>

#define DD 64      // input dim
#define HH 64      // hidden dim
#define OUTD 8     // output dim
#define NG 128     // num graphs
#define PSPLIT 8   // partial blocks per graph in pooling
#define NB 512     // bins for two-level CSR build
#define CAPD 3072  // per-bin record capacity
#define BIN_CHUNK 4096

typedef short short8 __attribute__((ext_vector_type(8)));
typedef float f32x4 __attribute__((ext_vector_type(4)));

__device__ __forceinline__ float sigmoidf_(float v) { return 1.0f / (1.0f + __expf(-v)); }
__device__ __forceinline__ unsigned short f2bf(float f) {
    unsigned u = __float_as_uint(f);
    unsigned r = u + 0x7FFFu + ((u >> 16) & 1u);
    return (unsigned short)(r >> 16);
}
__device__ __forceinline__ float bf2f(unsigned short b) {
    return __uint_as_float(((unsigned)b) << 16);
}

// ---- init: bin cursors=0, gemb=0, graph bounds (single block) ----
__global__ void init_kernel(int* gcur, int* scur, float* gemb,
                            const int* __restrict__ batch, int* __restrict__ starts, int N) {
    int t = threadIdx.x;
    for (int i = t; i < NB; i += 256) { gcur[i] = 0; scur[i] = 0; }
    for (int i = t; i < NG * HH; i += 256) gemb[i] = 0.0f;
    if (t <= NG) {
        int g = t, lo = 0, hi = N;
        while (lo < hi) {
            int mid = (lo + hi) >> 1;
            if (batch[mid] < g) lo = mid + 1; else hi = mid;
        }
        starts[g] = lo;
    }
}

// ---- phase 1: bin edges by dest (8B recs) + sources (1B recs); tail blocks do x->bf16 ----
__global__ __launch_bounds__(256)
void bin_xcvt_kernel(const int* __restrict__ ei, const float* __restrict__ ea,
                     int* gcur, int* scur, int2* __restrict__ dreg,
                     unsigned char* __restrict__ sreg, int E, int range, int nbin,
                     const float4* __restrict__ x4, uint4* __restrict__ xbf, int n8) {
    if (blockIdx.x >= nbin) {
        int i = (blockIdx.x - nbin) * 256 + threadIdx.x;
        if (i < n8) {
            float4 a = x4[i * 2], b = x4[i * 2 + 1];
            uint4 o;
            o.x = (unsigned)f2bf(a.x) | ((unsigned)f2bf(a.y) << 16);
            o.y = (unsigned)f2bf(a.z) | ((unsigned)f2bf(a.w) << 16);
            o.z = (unsigned)f2bf(b.x) | ((unsigned)f2bf(b.y) << 16);
            o.w = (unsigned)f2bf(b.z) | ((unsigned)f2bf(b.w) << 16);
            xbf[i] = o;
        }
        return;
    }
    __shared__ int dcnt[NB], scnt[NB], dbase[NB], sbase[NB];
    int t = threadIdx.x;
    for (int j = t; j < NB; j += 256) { dcnt[j] = 0; scnt[j] = 0; }
    __syncthreads();
    int e0 = blockIdx.x * BIN_CHUNK;
    int lim = min(BIN_CHUNK, E - e0);
    for (int i = t; i < lim; i += 256) {
        int e = e0 + i;
        atomicAdd(&dcnt[ei[E + e] / range], 1);
        atomicAdd(&scnt[ei[e] / range], 1);
    }
    __syncthreads();
    for (int j = t; j < NB; j += 256) {
        int dc = dcnt[j], sc = scnt[j];
        dbase[j] = dc ? atomicAdd(&gcur[j], dc) : 0;
        sbase[j] = sc ? atomicAdd(&scur[j], sc) : 0;
        dcnt[j] = 0; scnt[j] = 0;
    }
    __syncthreads();
    for (int i = t; i < lim; i += 256) {
        int e = e0 + i;
        int c = ei[E + e];
        int r = ei[e];
        int b = c / range, cl = c - b * range;
        int pos = dbase[b] + atomicAdd(&dcnt[b], 1);
        if (pos < CAPD)
            dreg[(size_t)b * CAPD + pos] = make_int2(r | (cl << 20), __float_as_int(ea[e]));
        int sb = r / range;
        int sp = sbase[sb] + atomicAdd(&scnt[sb], 1);
        if (sp < CAPD)
            sreg[(size_t)sb * CAPD + sp] = (unsigned char)(r - sb * range);
    }
}

// ---- phase 2a: per-bin source count -> dis = rsqrt(1 + outdeg) ----
__global__ __launch_bounds__(256)
void deg_kernel(const unsigned char* __restrict__ sreg, const int* __restrict__ scur,
                float* __restrict__ dis, int N, int range) {
    __shared__ int cnt[257];
    int t = threadIdx.x, b = blockIdx.x;
    for (int j = t; j <= range; j += 256) cnt[j] = 0;
    __syncthreads();
    int n = min(scur[b], CAPD);
    const unsigned char* p = sreg + (size_t)b * CAPD;
    for (int i = t; i < n; i += 256) atomicAdd(&cnt[p[i]], 1);
    __syncthreads();
    for (int j = t; j < range; j += 256) {
        int node = b * range + j;
        if (node < N) dis[node] = rsqrtf(1.0f + (float)cnt[j]);
    }
}

// ---- phase 2b: per-bin exact CSR + pre-multiplied coef ----
__global__ __launch_bounds__(256)
void csr_kernel(int2* __restrict__ dreg, const int* __restrict__ gcur,
                const float* __restrict__ dis,
                int* __restrict__ colstart, int* __restrict__ colcnt,
                int N, int range) {
    __shared__ int2 recs[CAPD];
    __shared__ int cnt[257], offs_s[257], sc[256];
    int t = threadIdx.x, b = blockIdx.x;
    int n = min(gcur[b], CAPD);
    size_t base = (size_t)b * CAPD;
    for (int i = t; i < n; i += 256) recs[i] = dreg[base + i];
    for (int j = t; j <= range; j += 256) cnt[j] = 0;
    __syncthreads();
    for (int i = t; i < n; i += 256) atomicAdd(&cnt[recs[i].x >> 20], 1);
    __syncthreads();
    int my = (t < range) ? cnt[t] : 0;
    sc[t] = my;
    __syncthreads();
    for (int off = 1; off < 256; off <<= 1) {
        int v = (t >= off) ? sc[t - off] : 0;
        __syncthreads();
        sc[t] += v;
        __syncthreads();
    }
    int ex = sc[t] - my;
    if (t < range) {
        offs_s[t] = ex;
        int node = b * range + t;
        if (node < N) { colstart[node] = (int)(base + ex); colcnt[node] = my; }
    }
    for (int j = t; j <= range; j += 256) cnt[j] = 0;
    __syncthreads();
    for (int i = t; i < n; i += 256) {
        int2 rc = recs[i];
        int cl = rc.x >> 20;
        int r = rc.x & 0xFFFFF;
        float coef = __int_as_float(rc.y) * dis[r] * dis[b * range + cl];
        int pos = offs_s[cl] + atomicAdd(&cnt[cl], 1);
        dreg[base + pos] = make_int2(r, __float_as_int(coef));
    }
}

// ---- fused gather + MFMA GEMM1 + tanh + out-head; 64 nodes/block (16/wave) ----
__global__ __launch_bounds__(256)
void gh_kernel(const int2* __restrict__ recs,
               const int* __restrict__ colstart, const int* __restrict__ colcnt,
               const float* __restrict__ dis,
               const unsigned short* __restrict__ xbf,
               const float* __restrict__ W1, const float* __restrict__ b1,
               const float* __restrict__ W2, const float* __restrict__ b2,
               unsigned short* __restrict__ hb, float* __restrict__ outp, int N) {
    __shared__ __align__(16) float atile[4][16][68];
    __shared__ __align__(16) float htile[4][16][68];
    int tid = threadIdx.x;
    int l = tid & 63, w = tid >> 6;
    int col = l & 15, kg = l >> 4;
    int half = l >> 5, d2 = l & 31;

    // W1/W2 B-frags: B[k][c] = W[c][k]; lane: c = 16*ct+col, k = 32*kt+8*kg+j
    short8 w1f[4][2];
    #pragma unroll
    for (int ct = 0; ct < 4; ++ct)
        #pragma unroll
        for (int kt = 0; kt < 2; ++kt) {
            const float* src = W1 + (16 * ct + col) * DD + 32 * kt + 8 * kg;
            short8 f;
            #pragma unroll
            for (int j = 0; j < 8; ++j) f[j] = (short)f2bf(src[j]);
            w1f[ct][kt] = f;
        }
    short8 w2f[2];
    #pragma unroll
    for (int kt = 0; kt < 2; ++kt) {
        short8 f;
        #pragma unroll
        for (int j = 0; j < 8; ++j)
            f[j] = (col < OUTD) ? (short)f2bf(W2[col * HH + 32 * kt + 8 * kg + j]) : (short)0;
        w2f[kt] = f;
    }
    float b1v[4];
    #pragma unroll
    for (int ct = 0; ct < 4; ++ct) b1v[ct] = b1[16 * ct + col];
    float b2v = (col < OUTD) ? b2[col] : 0.f;

    int base = (blockIdx.x * 4 + w) * 16;

    // ---- gather: 2 nodes per iteration (32 lanes each, u32 = 2 bf16 per lane) ----
    for (int it = 0; it < 8; ++it) {
        int node = base + 2 * it + half;
        bool v = node < N;
        float s = v ? dis[node] : 0.f;
        unsigned xv = v ? *(const unsigned*)(xbf + (size_t)node * DD + 2 * d2) : 0u;
        float a0 = s * s * __uint_as_float(xv << 16);
        float a1 = s * s * __uint_as_float(xv & 0xFFFF0000u);
        float c0acc = 0.f, c1acc = 0.f;
        int cnt = v ? colcnt[node] : 0;
        const int2* p = recs + (v ? colstart[node] : 0);
        int k = 0;
        for (; k + 4 <= cnt; k += 4) {
            int2 r0 = p[k], r1 = p[k + 1], r2 = p[k + 2], r3 = p[k + 3];
            unsigned q0 = *(const unsigned*)(xbf + (size_t)r0.x * DD + 2 * d2);
            unsigned q1 = *(const unsigned*)(xbf + (size_t)r1.x * DD + 2 * d2);
            unsigned q2 = *(const unsigned*)(xbf + (size_t)r2.x * DD + 2 * d2);
            unsigned q3 = *(const unsigned*)(xbf + (size_t)r3.x * DD + 2 * d2);
            float c0 = __int_as_float(r0.y), c1 = __int_as_float(r1.y);
            float c2 = __int_as_float(r2.y), c3 = __int_as_float(r3.y);
            a0 += c0 * __uint_as_float(q0 << 16);
            a1 += c0 * __uint_as_float(q0 & 0xFFFF0000u);
            c0acc += c1 * __uint_as_float(q1 << 16);
            c1acc += c1 * __uint_as_float(q1 & 0xFFFF0000u);
            a0 += c2 * __uint_as_float(q2 << 16);
            a1 += c2 * __uint_as_float(q2 & 0xFFFF0000u);
            c0acc += c3 * __uint_as_float(q3 << 16);
            c1acc += c3 * __uint_as_float(q3 & 0xFFFF0000u);
        }
        for (; k < cnt; ++k) {
            int2 r0 = p[k];
            unsigned q0 = *(const unsigned*)(xbf + (size_t)r0.x * DD + 2 * d2);
            float c0 = __int_as_float(r0.y);
            a0 += c0 * __uint_as_float(q0 << 16);
            a1 += c0 * __uint_as_float(q0 & 0xFFFF0000u);
        }
        atile[w][2 * it + half][2 * d2]     = a0 + c0acc;
        atile[w][2 * it + half][2 * d2 + 1] = a1 + c1acc;
    }
    __syncthreads();

    // ---- GEMM1: A-frags from LDS tile ----
    short8 af[2];
    #pragma unroll
    for (int kt = 0; kt < 2; ++kt) {
        const float* src = &atile[w][col][32 * kt + 8 * kg];
        float4 lo = *(const float4*)src;
        float4 hi = *(const float4*)(src + 4);
        short8 f;
        f[0] = (short)f2bf(lo.x); f[1] = (short)f2bf(lo.y);
        f[2] = (short)f2bf(lo.z); f[3] = (short)f2bf(lo.w);
        f[4] = (short)f2bf(hi.x); f[5] = (short)f2bf(hi.y);
        f[6] = (short)f2bf(hi.z); f[7] = (short)f2bf(hi.w);
        af[kt] = f;
    }
    #pragma unroll
    for (int ct = 0; ct < 4; ++ct) {
        f32x4 acc = {0.f, 0.f, 0.f, 0.f};
        acc = __builtin_amdgcn_mfma_f32_16x16x32_bf16(af[0], w1f[ct][0], acc, 0, 0, 0);
        acc = __builtin_amdgcn_mfma_f32_16x16x32_bf16(af[1], w1f[ct][1], acc, 0, 0, 0);
        #pragma unroll
        for (int jr = 0; jr < 4; ++jr) {
            float v = acc[jr] + b1v[ct];
            float ez = __expf(2.f * v);
            htile[w][4 * kg + jr][16 * ct + col] = (ez - 1.f) / (ez + 1.f);
        }
    }
    __syncthreads();

    // ---- coalesced bf16 h store (for pooling) ----
    for (int it = 0; it < 8; ++it) {
        int node = base + 2 * it + half;
        if (node < N) {
            float h0 = htile[w][2 * it + half][2 * d2];
            float h1 = htile[w][2 * it + half][2 * d2 + 1];
            unsigned pk = (unsigned)f2bf(h0) | ((unsigned)f2bf(h1) << 16);
            *(unsigned*)(hb + (size_t)node * HH + 2 * d2) = pk;
        }
    }

    // ---- GEMM2 (out head) ----
    short8 hf[2];
    #pragma unroll
    for (int kt = 0; kt < 2; ++kt) {
        const float* src = &htile[w][col][32 * kt + 8 * kg];
        float4 lo = *(const float4*)src;
        float4 hi = *(const float4*)(src + 4);
        short8 f;
        f[0] = (short)f2bf(lo.x); f[1] = (short)f2bf(lo.y);
        f[2] = (short)f2bf(lo.z); f[3] = (short)f2bf(lo.w);
        f[4] = (short)f2bf(hi.x); f[5] = (short)f2bf(hi.y);
        f[6] = (short)f2bf(hi.z); f[7] = (short)f2bf(hi.w);
        hf[kt] = f;
    }
    f32x4 acc2 = {0.f, 0.f, 0.f, 0.f};
    acc2 = __builtin_amdgcn_mfma_f32_16x16x32_bf16(hf[0], w2f[0], acc2, 0, 0, 0);
    acc2 = __builtin_amdgcn_mfma_f32_16x16x32_bf16(hf[1], w2f[1], acc2, 0, 0, 0);
    if (col < OUTD) {
        #pragma unroll
        for (int jr = 0; jr < 4; ++jr) {
            int node = base + 4 * kg + jr;
            if (node < N) outp[(size_t)node * OUTD + col] = sigmoidf_(acc2[jr] + b2v);
        }
    }
}

// ---- mean-pool numerator over bf16 h ----
__global__ void pool_kernel(const unsigned short* __restrict__ hb,
                            const int* __restrict__ starts,
                            float* __restrict__ gemb) {
    int g = blockIdx.x / PSPLIT;
    int part = blockIdx.x % PSPLIT;
    int s = starts[g], e = starts[g + 1];
    int tid = threadIdx.x;
    int hc = tid & 63, nl = tid >> 6;
    float sum = 0.0f;
    for (int n = s + part * 4 + nl; n < e; n += PSPLIT * 4)
        sum += bf2f(hb[(size_t)n * HH + hc]);
    __shared__ float red[4][HH];
    red[nl][hc] = sum;
    __syncthreads();
    if (nl == 0) {
        float v = red[0][hc] + red[1][hc] + red[2][hc] + red[3][hc];
        atomicAdd(&gemb[g * HH + hc], v);
    }
}

// ---- optimal head ----
__global__ void optimal_kernel(const float* __restrict__ gemb,
                               const int* __restrict__ starts,
                               const float* __restrict__ Wopt,
                               const float* __restrict__ bopt,
                               float* __restrict__ out2) {
    int g = blockIdx.x;
    int d = threadIdx.x;
    float c = fmaxf((float)(starts[g + 1] - starts[g]), 1.0f);
    float v = gemb[g * HH + d] / c * Wopt[d];
    #pragma unroll
    for (int off = 32; off > 0; off >>= 1) v += __shfl_down(v, off);
    if (d == 0) out2[g] = 1.0f / (1.0f + __expf(-(v + bopt[0])));
}

extern "C" void kernel_launch(void* const* d_in, const int* in_sizes, int n_in,
                              void* d_out, int out_size, void* d_ws, size_t ws_size,
                              hipStream_t stream) {
    const float* x     = (const float*)d_in[0];
    const int*   ei    = (const int*)d_in[1];
    const float* ea    = (const float*)d_in[2];
    const int*   batch = (const int*)d_in[3];
    const float* W1    = (const float*)d_in[4];
    const float* b1    = (const float*)d_in[5];
    const float* W2    = (const float*)d_in[6];
    const float* b2    = (const float*)d_in[7];
    const float* Wopt  = (const float*)d_in[8];
    const float* bopt  = (const float*)d_in[9];

    int N = in_sizes[0] / DD;
    int E = in_sizes[2];
    int range = (N + NB - 1) / NB;     // 196 for N=100000 (<= 256)

    float* out  = (float*)d_out;               // [N, 8]
    float* out2 = out + (size_t)N * OUTD;      // [G]

    // ws: dis[N] | colstart[N] | colcnt[N] | gemb | starts | gcur | scur |
    //     dreg[NB*CAPD]int2 | sreg[NB*CAPD]u8 | xbf[N*64]u16 | hb[N*64]u16
    char* p = (char*)d_ws;
    float* dis      = (float*)p;  p += (size_t)N * 4;
    int*   colstart = (int*)p;    p += (size_t)N * 4;
    int*   colcnt   = (int*)p;    p += (size_t)N * 4;
    float* gemb     = (float*)p;  p += (size_t)NG * HH * 4;
    int*   starts   = (int*)p;    p += (size_t)(NG + 2) * 4;
    int*   gcur     = (int*)p;    p += (size_t)NB * 4;
    int*   scur     = (int*)p;    p += (size_t)NB * 4;
    uintptr_t up = (uintptr_t)p; up = (up + 15) & ~(uintptr_t)15; p = (char*)up;
    int2* dreg = (int2*)p;        p += (size_t)NB * CAPD * 8;
    unsigned char* sreg = (unsigned char*)p; p += (size_t)NB * CAPD;
    up = (uintptr_t)p; up = (up + 15) & ~(uintptr_t)15; p = (char*)up;
    unsigned short* xbf = (unsigned short*)p; p += (size_t)N * DD * 2;
    unsigned short* hb  = (unsigned short*)p;

    int n8 = N * DD / 8;
    int nbin = (E + BIN_CHUNK - 1) / BIN_CHUNK;
    int nxc = (n8 + 255) / 256;

    init_kernel<<<1, 256, 0, stream>>>(gcur, scur, gemb, batch, starts, N);
    bin_xcvt_kernel<<<nbin + nxc, 256, 0, stream>>>(ei, ea, gcur, scur, dreg, sreg,
                                                    E, range, nbin,
                                                    (const float4*)x, (uint4*)xbf, n8);
    deg_kernel<<<NB, 256, 0, stream>>>(sreg, scur, dis, N, range);
    csr_kernel<<<NB, 256, 0, stream>>>(dreg, gcur, dis, colstart, colcnt, N, range);

    int nblk = (N + 63) / 64;
    gh_kernel<<<nblk, 256, 0, stream>>>(dreg, colstart, colcnt, dis, xbf,
                                        W1, b1, W2, b2, hb, out, N);

    pool_kernel<<<NG * PSPLIT, 256, 0, stream>>>(hb, starts, gemb);
    optimal_kernel<<<NG, 64, 0, stream>>>(gemb, starts, Wopt, bopt, out2);
}

// Round 9
// 147.370 us; speedup vs baseline: 1.2807x; 1.2807x over previous
//
#include <hip/hip_runtime.h>
#include <math.h>
#include <stdint.h>

#define DD 64      // input dim
#define HH 64      // hidden dim
#define OUTD 8     // output dim
#define NG 128     // num graphs
#define PSPLIT 8   // partial blocks per graph in pooling
#define NB 512     // bins for two-level CSR build
#define CAPD 3072  // per-bin record capacity
#define BIN_CHUNK 4096

typedef short short8 __attribute__((ext_vector_type(8)));
typedef float f32x4 __attribute__((ext_vector_type(4)));

__device__ __forceinline__ float sigmoidf_(float v) { return 1.0f / (1.0f + __expf(-v)); }
__device__ __forceinline__ unsigned short f2bf(float f) {
    unsigned u = __float_as_uint(f);
    unsigned r = u + 0x7FFFu + ((u >> 16) & 1u);
    return (unsigned short)(r >> 16);
}
__device__ __forceinline__ float bf2f(unsigned short b) {
    return __uint_as_float(((unsigned)b) << 16);
}
__device__ __forceinline__ float bflo(unsigned q) { return __uint_as_float(q << 16); }
__device__ __forceinline__ float bfhi(unsigned q) { return __uint_as_float(q & 0xFFFF0000u); }

// ---- init: bin cursors=0, gemb=0, graph bounds (single block) ----
__global__ void init_kernel(int* gcur, int* scur, float* gemb,
                            const int* __restrict__ batch, int* __restrict__ starts, int N) {
    int t = threadIdx.x;
    for (int i = t; i < NB; i += 256) { gcur[i] = 0; scur[i] = 0; }
    for (int i = t; i < NG * HH; i += 256) gemb[i] = 0.0f;
    if (t <= NG) {
        int g = t, lo = 0, hi = N;
        while (lo < hi) {
            int mid = (lo + hi) >> 1;
            if (batch[mid] < g) lo = mid + 1; else hi = mid;
        }
        starts[g] = lo;
    }
}

// ---- phase 1: bin edges by dest (8B recs) + sources (1B recs); tail blocks do x->bf16 ----
__global__ __launch_bounds__(256)
void bin_xcvt_kernel(const int* __restrict__ ei, const float* __restrict__ ea,
                     int* gcur, int* scur, int2* __restrict__ dreg,
                     unsigned char* __restrict__ sreg, int E, int range, int nbin,
                     const float4* __restrict__ x4, uint4* __restrict__ xbf, int n8) {
    if (blockIdx.x >= nbin) {
        int i = (blockIdx.x - nbin) * 256 + threadIdx.x;
        if (i < n8) {
            float4 a = x4[i * 2], b = x4[i * 2 + 1];
            uint4 o;
            o.x = (unsigned)f2bf(a.x) | ((unsigned)f2bf(a.y) << 16);
            o.y = (unsigned)f2bf(a.z) | ((unsigned)f2bf(a.w) << 16);
            o.z = (unsigned)f2bf(b.x) | ((unsigned)f2bf(b.y) << 16);
            o.w = (unsigned)f2bf(b.z) | ((unsigned)f2bf(b.w) << 16);
            xbf[i] = o;
        }
        return;
    }
    __shared__ int dcnt[NB], scnt[NB], dbase[NB], sbase[NB];
    int t = threadIdx.x;
    for (int j = t; j < NB; j += 256) { dcnt[j] = 0; scnt[j] = 0; }
    __syncthreads();
    int e0 = blockIdx.x * BIN_CHUNK;
    int lim = min(BIN_CHUNK, E - e0);
    for (int i = t; i < lim; i += 256) {
        int e = e0 + i;
        atomicAdd(&dcnt[ei[E + e] / range], 1);
        atomicAdd(&scnt[ei[e] / range], 1);
    }
    __syncthreads();
    for (int j = t; j < NB; j += 256) {
        int dc = dcnt[j], sc = scnt[j];
        dbase[j] = dc ? atomicAdd(&gcur[j], dc) : 0;
        sbase[j] = sc ? atomicAdd(&scur[j], sc) : 0;
        dcnt[j] = 0; scnt[j] = 0;
    }
    __syncthreads();
    for (int i = t; i < lim; i += 256) {
        int e = e0 + i;
        int c = ei[E + e];
        int r = ei[e];
        int b = c / range, cl = c - b * range;
        int pos = dbase[b] + atomicAdd(&dcnt[b], 1);
        if (pos < CAPD)
            dreg[(size_t)b * CAPD + pos] = make_int2(r | (cl << 20), __float_as_int(ea[e]));
        int sb = r / range;
        int sp = sbase[sb] + atomicAdd(&scnt[sb], 1);
        if (sp < CAPD)
            sreg[(size_t)sb * CAPD + sp] = (unsigned char)(r - sb * range);
    }
}

// ---- phase 2a: per-bin source count -> dis = rsqrt(1 + outdeg) ----
__global__ __launch_bounds__(256)
void deg_kernel(const unsigned char* __restrict__ sreg, const int* __restrict__ scur,
                float* __restrict__ dis, int N, int range) {
    __shared__ int cnt[257];
    int t = threadIdx.x, b = blockIdx.x;
    for (int j = t; j <= range; j += 256) cnt[j] = 0;
    __syncthreads();
    int n = min(scur[b], CAPD);
    const unsigned char* p = sreg + (size_t)b * CAPD;
    for (int i = t; i < n; i += 256) atomicAdd(&cnt[p[i]], 1);
    __syncthreads();
    for (int j = t; j < range; j += 256) {
        int node = b * range + j;
        if (node < N) dis[node] = rsqrtf(1.0f + (float)cnt[j]);
    }
}

// ---- phase 2b: per-bin exact CSR + pre-multiplied coef ----
__global__ __launch_bounds__(256)
void csr_kernel(int2* __restrict__ dreg, const int* __restrict__ gcur,
                const float* __restrict__ dis,
                int* __restrict__ colstart, int* __restrict__ colcnt,
                int N, int range) {
    __shared__ int2 recs[CAPD];
    __shared__ int cnt[257], offs_s[257], sc[256];
    int t = threadIdx.x, b = blockIdx.x;
    int n = min(gcur[b], CAPD);
    size_t base = (size_t)b * CAPD;
    for (int i = t; i < n; i += 256) recs[i] = dreg[base + i];
    for (int j = t; j <= range; j += 256) cnt[j] = 0;
    __syncthreads();
    for (int i = t; i < n; i += 256) atomicAdd(&cnt[recs[i].x >> 20], 1);
    __syncthreads();
    int my = (t < range) ? cnt[t] : 0;
    sc[t] = my;
    __syncthreads();
    for (int off = 1; off < 256; off <<= 1) {
        int v = (t >= off) ? sc[t - off] : 0;
        __syncthreads();
        sc[t] += v;
        __syncthreads();
    }
    int ex = sc[t] - my;
    if (t < range) {
        offs_s[t] = ex;
        int node = b * range + t;
        if (node < N) { colstart[node] = (int)(base + ex); colcnt[node] = my; }
    }
    for (int j = t; j <= range; j += 256) cnt[j] = 0;
    __syncthreads();
    for (int i = t; i < n; i += 256) {
        int2 rc = recs[i];
        int cl = rc.x >> 20;
        int r = rc.x & 0xFFFFF;
        float coef = __int_as_float(rc.y) * dis[r] * dis[b * range + cl];
        int pos = offs_s[cl] + atomicAdd(&cnt[cl], 1);
        dreg[base + pos] = make_int2(r, __float_as_int(coef));
    }
}

// ---- gather: 2 nodes per wave (32 lanes, 2 dims/lane), lean, writes packed bf16 ----
__global__ __launch_bounds__(256)
void gather_kernel(const int2* __restrict__ recs,
                   const int* __restrict__ colstart, const int* __restrict__ colcnt,
                   const float* __restrict__ dis,
                   const unsigned short* __restrict__ xbf,
                   unsigned* __restrict__ axb, int N) {
    int wid = blockIdx.x * 4 + (threadIdx.x >> 6);
    int l = threadIdx.x & 63;
    int half = l >> 5, d2 = l & 31;
    int node = wid * 2 + half;
    bool v = node < N;
    float s = v ? dis[node] : 0.f;
    unsigned xv = v ? *(const unsigned*)(xbf + (size_t)node * DD + 2 * d2) : 0u;
    float a0 = s * s * bflo(xv);
    float a1 = s * s * bfhi(xv);
    float b0 = 0.f, b1 = 0.f;
    int cnt = v ? colcnt[node] : 0;
    const int2* p = recs + (v ? colstart[node] : 0);
    int k = 0;
    for (; k + 4 <= cnt; k += 4) {
        int2 r0 = p[k], r1 = p[k + 1], r2 = p[k + 2], r3 = p[k + 3];
        unsigned q0 = *(const unsigned*)(xbf + (size_t)r0.x * DD + 2 * d2);
        unsigned q1 = *(const unsigned*)(xbf + (size_t)r1.x * DD + 2 * d2);
        unsigned q2 = *(const unsigned*)(xbf + (size_t)r2.x * DD + 2 * d2);
        unsigned q3 = *(const unsigned*)(xbf + (size_t)r3.x * DD + 2 * d2);
        float c0 = __int_as_float(r0.y), c1 = __int_as_float(r1.y);
        float c2 = __int_as_float(r2.y), c3 = __int_as_float(r3.y);
        a0 += c0 * bflo(q0); a1 += c0 * bfhi(q0);
        b0 += c1 * bflo(q1); b1 += c1 * bfhi(q1);
        a0 += c2 * bflo(q2); a1 += c2 * bfhi(q2);
        b0 += c3 * bflo(q3); b1 += c3 * bfhi(q3);
    }
    for (; k < cnt; ++k) {
        int2 r0 = p[k];
        unsigned q0 = *(const unsigned*)(xbf + (size_t)r0.x * DD + 2 * d2);
        float c0 = __int_as_float(r0.y);
        a0 += c0 * bflo(q0); a1 += c0 * bfhi(q0);
    }
    if (v) {
        float v0 = a0 + b0, v1 = a1 + b1;
        axb[(size_t)node * (DD / 2) + d2] = (unsigned)f2bf(v0) | ((unsigned)f2bf(v1) << 16);
    }
}

// ---- MFMA head: A-frags direct from bf16 aggr; h via LDS transpose; out + hb stores ----
__global__ __launch_bounds__(256)
void head_kernel(const unsigned short* __restrict__ axb,
                 const float* __restrict__ W1, const float* __restrict__ b1,
                 const float* __restrict__ W2, const float* __restrict__ b2,
                 unsigned short* __restrict__ hb, float* __restrict__ outp, int N) {
    __shared__ __align__(16) float htile[4][16][68];
    int tid = threadIdx.x;
    int l = tid & 63, w = tid >> 6;
    int col = l & 15, kg = l >> 4;
    int half = l >> 5, d2 = l & 31;

    short8 w1f[4][2];
    #pragma unroll
    for (int ct = 0; ct < 4; ++ct)
        #pragma unroll
        for (int kt = 0; kt < 2; ++kt) {
            const float* src = W1 + (16 * ct + col) * DD + 32 * kt + 8 * kg;
            short8 f;
            #pragma unroll
            for (int j = 0; j < 8; ++j) f[j] = (short)f2bf(src[j]);
            w1f[ct][kt] = f;
        }
    short8 w2f[2];
    #pragma unroll
    for (int kt = 0; kt < 2; ++kt) {
        short8 f;
        #pragma unroll
        for (int j = 0; j < 8; ++j)
            f[j] = (col < OUTD) ? (short)f2bf(W2[col * HH + 32 * kt + 8 * kg + j]) : (short)0;
        w2f[kt] = f;
    }
    float b1v[4];
    #pragma unroll
    for (int ct = 0; ct < 4; ++ct) b1v[ct] = b1[16 * ct + col];
    float b2v = (col < OUTD) ? b2[col] : 0.f;

    int ngrp = (N + 15) >> 4;
    int g = blockIdx.x * 4 + w;
    bool act = g < ngrp;
    int base = act ? g * 16 : 0;
    int rr = min(base + col, N - 1);

    short8 af[2];
    #pragma unroll
    for (int kt = 0; kt < 2; ++kt)
        af[kt] = *(const short8*)(axb + (size_t)rr * DD + 32 * kt + 8 * kg);

    #pragma unroll
    for (int ct = 0; ct < 4; ++ct) {
        f32x4 acc = {0.f, 0.f, 0.f, 0.f};
        acc = __builtin_amdgcn_mfma_f32_16x16x32_bf16(af[0], w1f[ct][0], acc, 0, 0, 0);
        acc = __builtin_amdgcn_mfma_f32_16x16x32_bf16(af[1], w1f[ct][1], acc, 0, 0, 0);
        #pragma unroll
        for (int jr = 0; jr < 4; ++jr) {
            float v = acc[jr] + b1v[ct];
            float ez = __expf(2.f * v);
            htile[w][4 * kg + jr][16 * ct + col] = (ez - 1.f) / (ez + 1.f);
        }
    }
    __syncthreads();

    // coalesced bf16 h store (for pooling)
    #pragma unroll
    for (int it = 0; it < 8; ++it) {
        int node = base + 2 * it + half;
        if (act && node < N) {
            float h0 = htile[w][2 * it + half][2 * d2];
            float h1 = htile[w][2 * it + half][2 * d2 + 1];
            *(unsigned*)(hb + (size_t)node * HH + 2 * d2) =
                (unsigned)f2bf(h0) | ((unsigned)f2bf(h1) << 16);
        }
    }

    // GEMM2 (out head)
    short8 hf[2];
    #pragma unroll
    for (int kt = 0; kt < 2; ++kt) {
        const float* src = &htile[w][col][32 * kt + 8 * kg];
        float4 lo = *(const float4*)src;
        float4 hi = *(const float4*)(src + 4);
        short8 f;
        f[0] = (short)f2bf(lo.x); f[1] = (short)f2bf(lo.y);
        f[2] = (short)f2bf(lo.z); f[3] = (short)f2bf(lo.w);
        f[4] = (short)f2bf(hi.x); f[5] = (short)f2bf(hi.y);
        f[6] = (short)f2bf(hi.z); f[7] = (short)f2bf(hi.w);
        hf[kt] = f;
    }
    f32x4 acc2 = {0.f, 0.f, 0.f, 0.f};
    acc2 = __builtin_amdgcn_mfma_f32_16x16x32_bf16(hf[0], w2f[0], acc2, 0, 0, 0);
    acc2 = __builtin_amdgcn_mfma_f32_16x16x32_bf16(hf[1], w2f[1], acc2, 0, 0, 0);
    if (act && col < OUTD) {
        #pragma unroll
        for (int jr = 0; jr < 4; ++jr) {
            int node = base + 4 * kg + jr;
            if (node < N) outp[(size_t)node * OUTD + col] = sigmoidf_(acc2[jr] + b2v);
        }
    }
}

// ---- mean-pool numerator over bf16 h ----
__global__ void pool_kernel(const unsigned short* __restrict__ hb,
                            const int* __restrict__ starts,
                            float* __restrict__ gemb) {
    int g = blockIdx.x / PSPLIT;
    int part = blockIdx.x % PSPLIT;
    int s = starts[g], e = starts[g + 1];
    int tid = threadIdx.x;
    int hc = tid & 63, nl = tid >> 6;
    float sum = 0.0f;
    for (int n = s + part * 4 + nl; n < e; n += PSPLIT * 4)
        sum += bf2f(hb[(size_t)n * HH + hc]);
    __shared__ float red[4][HH];
    red[nl][hc] = sum;
    __syncthreads();
    if (nl == 0) {
        float v = red[0][hc] + red[1][hc] + red[2][hc] + red[3][hc];
        atomicAdd(&gemb[g * HH + hc], v);
    }
}

// ---- optimal head ----
__global__ void optimal_kernel(const float* __restrict__ gemb,
                               const int* __restrict__ starts,
                               const float* __restrict__ Wopt,
                               const float* __restrict__ bopt,
                               float* __restrict__ out2) {
    int g = blockIdx.x;
    int d = threadIdx.x;
    float c = fmaxf((float)(starts[g + 1] - starts[g]), 1.0f);
    float v = gemb[g * HH + d] / c * Wopt[d];
    #pragma unroll
    for (int off = 32; off > 0; off >>= 1) v += __shfl_down(v, off);
    if (d == 0) out2[g] = 1.0f / (1.0f + __expf(-(v + bopt[0])));
}

extern "C" void kernel_launch(void* const* d_in, const int* in_sizes, int n_in,
                              void* d_out, int out_size, void* d_ws, size_t ws_size,
                              hipStream_t stream) {
    const float* x     = (const float*)d_in[0];
    const int*   ei    = (const int*)d_in[1];
    const float* ea    = (const float*)d_in[2];
    const int*   batch = (const int*)d_in[3];
    const float* W1    = (const float*)d_in[4];
    const float* b1    = (const float*)d_in[5];
    const float* W2    = (const float*)d_in[6];
    const float* b2    = (const float*)d_in[7];
    const float* Wopt  = (const float*)d_in[8];
    const float* bopt  = (const float*)d_in[9];

    int N = in_sizes[0] / DD;
    int E = in_sizes[2];
    int range = (N + NB - 1) / NB;     // 196 for N=100000 (<= 256)

    float* out  = (float*)d_out;               // [N, 8]
    float* out2 = out + (size_t)N * OUTD;      // [G]

    // ws: dis[N] | colstart[N] | colcnt[N] | gemb | starts | gcur | scur |
    //     dreg[NB*CAPD]int2 | sreg[NB*CAPD]u8 | xbf[N*64]u16 | axb[N*32]u32 | hb[N*64]u16
    char* p = (char*)d_ws;
    float* dis      = (float*)p;  p += (size_t)N * 4;
    int*   colstart = (int*)p;    p += (size_t)N * 4;
    int*   colcnt   = (int*)p;    p += (size_t)N * 4;
    float* gemb     = (float*)p;  p += (size_t)NG * HH * 4;
    int*   starts   = (int*)p;    p += (size_t)(NG + 2) * 4;
    int*   gcur     = (int*)p;    p += (size_t)NB * 4;
    int*   scur     = (int*)p;    p += (size_t)NB * 4;
    uintptr_t up = (uintptr_t)p; up = (up + 15) & ~(uintptr_t)15; p = (char*)up;
    int2* dreg = (int2*)p;        p += (size_t)NB * CAPD * 8;
    unsigned char* sreg = (unsigned char*)p; p += (size_t)NB * CAPD;
    up = (uintptr_t)p; up = (up + 15) & ~(uintptr_t)15; p = (char*)up;
    unsigned short* xbf = (unsigned short*)p; p += (size_t)N * DD * 2;
    unsigned* axb = (unsigned*)p; p += (size_t)N * (DD / 2) * 4;
    unsigned short* hb  = (unsigned short*)p;

    int n8 = N * DD / 8;
    int nbin = (E + BIN_CHUNK - 1) / BIN_CHUNK;
    int nxc = (n8 + 255) / 256;

    init_kernel<<<1, 256, 0, stream>>>(gcur, scur, gemb, batch, starts, N);
    bin_xcvt_kernel<<<nbin + nxc, 256, 0, stream>>>(ei, ea, gcur, scur, dreg, sreg,
                                                    E, range, nbin,
                                                    (const float4*)x, (uint4*)xbf, n8);
    deg_kernel<<<NB, 256, 0, stream>>>(sreg, scur, dis, N, range);
    csr_kernel<<<NB, 256, 0, stream>>>(dreg, gcur, dis, colstart, colcnt, N, range);

    gather_kernel<<<(N + 7) / 8, 256, 0, stream>>>(dreg, colstart, colcnt, dis, xbf, axb, N);

    int ngrp = (N + 15) / 16;
    head_kernel<<<(ngrp + 3) / 4, 256, 0, stream>>>((const unsigned short*)axb,
                                                    W1, b1, W2, b2, hb, out, N);

    pool_kernel<<<NG * PSPLIT, 256, 0, stream>>>(hb, starts, gemb);
    optimal_kernel<<<NG, 64, 0, stream>>>(gemb, starts, Wopt, bopt, out2);
}

// Round 10
// 133.608 us; speedup vs baseline: 1.4126x; 1.1030x over previous
//
#include <hip/hip_runtime.h>
#include <math.h>
#include <stdint.h>

#define DD 64      // input dim
#define HH 64      // hidden dim
#define OUTD 8     // output dim
#define NG 128     // num graphs
#define PSPLIT 8   // partial blocks per graph in pooling
#define NB 512     // max bins (compile-time LDS size); used bins = ceil(N/256)
#define RSH 8      // range = 256 = 1<<RSH
#define RMSK 255
#define CAPD 3072  // per-bin record capacity (mean 2560, ~10 sigma margin, guarded)
#define BIN_CHUNK 4096
#define BT 1024    // bin block threads

typedef short short8 __attribute__((ext_vector_type(8)));
typedef float f32x4 __attribute__((ext_vector_type(4)));

__device__ __forceinline__ float sigmoidf_(float v) { return 1.0f / (1.0f + __expf(-v)); }
__device__ __forceinline__ unsigned short f2bf(float f) {
    unsigned u = __float_as_uint(f);
    unsigned r = u + 0x7FFFu + ((u >> 16) & 1u);
    return (unsigned short)(r >> 16);
}
__device__ __forceinline__ float bf2f(unsigned short b) {
    return __uint_as_float(((unsigned)b) << 16);
}
__device__ __forceinline__ float bflo(unsigned q) { return __uint_as_float(q << 16); }
__device__ __forceinline__ float bfhi(unsigned q) { return __uint_as_float(q & 0xFFFF0000u); }

__device__ __forceinline__ int lbound_(const int* __restrict__ batch, int N, int g) {
    int lo = 0, hi = N;
    while (lo < hi) { int m = (lo + hi) >> 1; if (batch[m] < g) lo = m + 1; else hi = m; }
    return lo;
}

// ---- phase 1: bin edges by dest (8B recs) + sources (1B recs); tail blocks do x->bf16 ----
__global__ __launch_bounds__(BT)
void bin_xcvt_kernel(const int* __restrict__ ei, const float* __restrict__ ea,
                     int* gcur, int* scur, int2* __restrict__ dreg,
                     unsigned char* __restrict__ sreg, int E, int nbin,
                     const float4* __restrict__ x4, uint4* __restrict__ xbf, int n8) {
    if (blockIdx.x >= nbin) {
        int i = (blockIdx.x - nbin) * BT + threadIdx.x;
        if (i < n8) {
            float4 a = x4[i * 2], b = x4[i * 2 + 1];
            uint4 o;
            o.x = (unsigned)f2bf(a.x) | ((unsigned)f2bf(a.y) << 16);
            o.y = (unsigned)f2bf(a.z) | ((unsigned)f2bf(a.w) << 16);
            o.z = (unsigned)f2bf(b.x) | ((unsigned)f2bf(b.y) << 16);
            o.w = (unsigned)f2bf(b.z) | ((unsigned)f2bf(b.w) << 16);
            xbf[i] = o;
        }
        return;
    }
    __shared__ int dcnt[NB], scnt[NB], dbase[NB], sbase[NB];
    int t = threadIdx.x;
    for (int j = t; j < NB; j += BT) { dcnt[j] = 0; scnt[j] = 0; }
    __syncthreads();
    int e0 = blockIdx.x * BIN_CHUNK;
    int lim = min(BIN_CHUNK, E - e0);
    int rv0 = 0, rv1 = 0, rv2 = 0, rv3 = 0;
    int cv0 = 0, cv1 = 0, cv2 = 0, cv3 = 0;
    float av0 = 0, av1 = 0, av2 = 0, av3 = 0;
    {
        int i;
        i = t;            if (i < lim) { rv0 = ei[e0+i]; cv0 = ei[E+e0+i]; av0 = ea[e0+i];
                                         atomicAdd(&dcnt[cv0 >> RSH], 1); atomicAdd(&scnt[rv0 >> RSH], 1); }
        i = t + BT;       if (i < lim) { rv1 = ei[e0+i]; cv1 = ei[E+e0+i]; av1 = ea[e0+i];
                                         atomicAdd(&dcnt[cv1 >> RSH], 1); atomicAdd(&scnt[rv1 >> RSH], 1); }
        i = t + 2 * BT;   if (i < lim) { rv2 = ei[e0+i]; cv2 = ei[E+e0+i]; av2 = ea[e0+i];
                                         atomicAdd(&dcnt[cv2 >> RSH], 1); atomicAdd(&scnt[rv2 >> RSH], 1); }
        i = t + 3 * BT;   if (i < lim) { rv3 = ei[e0+i]; cv3 = ei[E+e0+i]; av3 = ea[e0+i];
                                         atomicAdd(&dcnt[cv3 >> RSH], 1); atomicAdd(&scnt[rv3 >> RSH], 1); }
    }
    __syncthreads();
    for (int j = t; j < NB; j += BT) {
        int dc = dcnt[j], sc = scnt[j];
        dbase[j] = dc ? atomicAdd(&gcur[j], dc) : 0;
        sbase[j] = sc ? atomicAdd(&scur[j], sc) : 0;
        dcnt[j] = 0; scnt[j] = 0;
    }
    __syncthreads();
    #define EMIT(RR, CC, AA, II) do { \
        if ((II) < lim) { \
            int b_ = (CC) >> RSH, cl_ = (CC) & RMSK; \
            int pos_ = dbase[b_] + atomicAdd(&dcnt[b_], 1); \
            if (pos_ < CAPD) dreg[(size_t)b_ * CAPD + pos_] = make_int2((RR) | (cl_ << 20), __float_as_int(AA)); \
            int sb_ = (RR) >> RSH; \
            int sp_ = sbase[sb_] + atomicAdd(&scnt[sb_], 1); \
            if (sp_ < CAPD) sreg[(size_t)sb_ * CAPD + sp_] = (unsigned char)((RR) & RMSK); \
        } } while (0)
    EMIT(rv0, cv0, av0, t);
    EMIT(rv1, cv1, av1, t + BT);
    EMIT(rv2, cv2, av2, t + 2 * BT);
    EMIT(rv3, cv3, av3, t + 3 * BT);
    #undef EMIT
}

// ---- phase 2a: per-bin source count -> dis = rsqrt(1 + outdeg) ----
__global__ __launch_bounds__(256)
void deg_kernel(const unsigned char* __restrict__ sreg, const int* __restrict__ scur,
                float* __restrict__ dis, int N) {
    __shared__ int cnt[256];
    int t = threadIdx.x, b = blockIdx.x;
    cnt[t] = 0;
    __syncthreads();
    int n = min(scur[b], CAPD);
    const unsigned char* p = sreg + (size_t)b * CAPD;
    for (int i = t; i < n; i += 256) atomicAdd(&cnt[p[i]], 1);
    __syncthreads();
    int node = (b << RSH) + t;
    if (node < N) dis[node] = rsqrtf(1.0f + (float)cnt[t]);
}

// ---- phase 2b: per-bin exact CSR + pre-multiplied coef ----
__global__ __launch_bounds__(256)
void csr_kernel(int2* __restrict__ dreg, const int* __restrict__ gcur,
                const float* __restrict__ dis,
                int* __restrict__ colstart, int* __restrict__ colcnt, int N) {
    __shared__ int2 recs[CAPD];
    __shared__ int cnt[256], offs_s[256], sc[256];
    int t = threadIdx.x, b = blockIdx.x;
    int n = min(gcur[b], CAPD);
    size_t base = (size_t)b * CAPD;
    for (int i = t; i < n; i += 256) recs[i] = dreg[base + i];
    cnt[t] = 0;
    __syncthreads();
    for (int i = t; i < n; i += 256) atomicAdd(&cnt[recs[i].x >> 20], 1);
    __syncthreads();
    int my = cnt[t];
    sc[t] = my;
    __syncthreads();
    for (int off = 1; off < 256; off <<= 1) {
        int v = (t >= off) ? sc[t - off] : 0;
        __syncthreads();
        sc[t] += v;
        __syncthreads();
    }
    int ex = sc[t] - my;
    offs_s[t] = ex;
    int node = (b << RSH) + t;
    if (node < N) { colstart[node] = (int)(base + ex); colcnt[node] = my; }
    cnt[t] = 0;
    __syncthreads();
    for (int i = t; i < n; i += 256) {
        int2 rc = recs[i];
        int cl = rc.x >> 20;
        int r = rc.x & 0xFFFFF;
        float coef = __int_as_float(rc.y) * dis[r] * dis[(b << RSH) + cl];
        int pos = offs_s[cl] + atomicAdd(&cnt[cl], 1);
        dreg[base + pos] = make_int2(r, __float_as_int(coef));
    }
}

// ---- gather: 2 nodes per wave (32 lanes, 2 dims/lane), lean, writes packed bf16 ----
__global__ __launch_bounds__(256)
void gather_kernel(const int2* __restrict__ recs,
                   const int* __restrict__ colstart, const int* __restrict__ colcnt,
                   const float* __restrict__ dis,
                   const unsigned short* __restrict__ xbf,
                   unsigned* __restrict__ axb, int N) {
    int wid = blockIdx.x * 4 + (threadIdx.x >> 6);
    int l = threadIdx.x & 63;
    int half = l >> 5, d2 = l & 31;
    int node = wid * 2 + half;
    bool v = node < N;
    float s = v ? dis[node] : 0.f;
    unsigned xv = v ? *(const unsigned*)(xbf + (size_t)node * DD + 2 * d2) : 0u;
    float a0 = s * s * bflo(xv);
    float a1 = s * s * bfhi(xv);
    float b0 = 0.f, b1 = 0.f;
    int cnt = v ? colcnt[node] : 0;
    const int2* p = recs + (v ? colstart[node] : 0);
    int k = 0;
    for (; k + 4 <= cnt; k += 4) {
        int2 r0 = p[k], r1 = p[k + 1], r2 = p[k + 2], r3 = p[k + 3];
        unsigned q0 = *(const unsigned*)(xbf + (size_t)r0.x * DD + 2 * d2);
        unsigned q1 = *(const unsigned*)(xbf + (size_t)r1.x * DD + 2 * d2);
        unsigned q2 = *(const unsigned*)(xbf + (size_t)r2.x * DD + 2 * d2);
        unsigned q3 = *(const unsigned*)(xbf + (size_t)r3.x * DD + 2 * d2);
        float c0 = __int_as_float(r0.y), c1 = __int_as_float(r1.y);
        float c2 = __int_as_float(r2.y), c3 = __int_as_float(r3.y);
        a0 += c0 * bflo(q0); a1 += c0 * bfhi(q0);
        b0 += c1 * bflo(q1); b1 += c1 * bfhi(q1);
        a0 += c2 * bflo(q2); a1 += c2 * bfhi(q2);
        b0 += c3 * bflo(q3); b1 += c3 * bfhi(q3);
    }
    for (; k < cnt; ++k) {
        int2 r0 = p[k];
        unsigned q0 = *(const unsigned*)(xbf + (size_t)r0.x * DD + 2 * d2);
        float c0 = __int_as_float(r0.y);
        a0 += c0 * bflo(q0); a1 += c0 * bfhi(q0);
    }
    if (v) {
        float v0 = a0 + b0, v1 = a1 + b1;
        axb[(size_t)node * (DD / 2) + d2] = (unsigned)f2bf(v0) | ((unsigned)f2bf(v1) << 16);
    }
}

// ---- MFMA head: A-frags direct from bf16 aggr; h via LDS transpose; out + hb stores ----
__global__ __launch_bounds__(256)
void head_kernel(const unsigned short* __restrict__ axb,
                 const float* __restrict__ W1, const float* __restrict__ b1,
                 const float* __restrict__ W2, const float* __restrict__ b2,
                 unsigned short* __restrict__ hb, float* __restrict__ outp, int N) {
    __shared__ __align__(16) float htile[4][16][68];
    int tid = threadIdx.x;
    int l = tid & 63, w = tid >> 6;
    int col = l & 15, kg = l >> 4;
    int half = l >> 5, d2 = l & 31;

    short8 w1f[4][2];
    #pragma unroll
    for (int ct = 0; ct < 4; ++ct)
        #pragma unroll
        for (int kt = 0; kt < 2; ++kt) {
            const float* src = W1 + (16 * ct + col) * DD + 32 * kt + 8 * kg;
            short8 f;
            #pragma unroll
            for (int j = 0; j < 8; ++j) f[j] = (short)f2bf(src[j]);
            w1f[ct][kt] = f;
        }
    short8 w2f[2];
    #pragma unroll
    for (int kt = 0; kt < 2; ++kt) {
        short8 f;
        #pragma unroll
        for (int j = 0; j < 8; ++j)
            f[j] = (col < OUTD) ? (short)f2bf(W2[col * HH + 32 * kt + 8 * kg + j]) : (short)0;
        w2f[kt] = f;
    }
    float b1v[4];
    #pragma unroll
    for (int ct = 0; ct < 4; ++ct) b1v[ct] = b1[16 * ct + col];
    float b2v = (col < OUTD) ? b2[col] : 0.f;

    int ngrp = (N + 15) >> 4;
    int g = blockIdx.x * 4 + w;
    bool act = g < ngrp;
    int base = act ? g * 16 : 0;
    int rr = min(base + col, N - 1);

    short8 af[2];
    #pragma unroll
    for (int kt = 0; kt < 2; ++kt)
        af[kt] = *(const short8*)(axb + (size_t)rr * DD + 32 * kt + 8 * kg);

    #pragma unroll
    for (int ct = 0; ct < 4; ++ct) {
        f32x4 acc = {0.f, 0.f, 0.f, 0.f};
        acc = __builtin_amdgcn_mfma_f32_16x16x32_bf16(af[0], w1f[ct][0], acc, 0, 0, 0);
        acc = __builtin_amdgcn_mfma_f32_16x16x32_bf16(af[1], w1f[ct][1], acc, 0, 0, 0);
        #pragma unroll
        for (int jr = 0; jr < 4; ++jr) {
            float v = acc[jr] + b1v[ct];
            float ez = __expf(2.f * v);
            htile[w][4 * kg + jr][16 * ct + col] = (ez - 1.f) / (ez + 1.f);
        }
    }
    __syncthreads();

    #pragma unroll
    for (int it = 0; it < 8; ++it) {
        int node = base + 2 * it + half;
        if (act && node < N) {
            float h0 = htile[w][2 * it + half][2 * d2];
            float h1 = htile[w][2 * it + half][2 * d2 + 1];
            *(unsigned*)(hb + (size_t)node * HH + 2 * d2) =
                (unsigned)f2bf(h0) | ((unsigned)f2bf(h1) << 16);
        }
    }

    short8 hf[2];
    #pragma unroll
    for (int kt = 0; kt < 2; ++kt) {
        const float* src = &htile[w][col][32 * kt + 8 * kg];
        float4 lo = *(const float4*)src;
        float4 hi = *(const float4*)(src + 4);
        short8 f;
        f[0] = (short)f2bf(lo.x); f[1] = (short)f2bf(lo.y);
        f[2] = (short)f2bf(lo.z); f[3] = (short)f2bf(lo.w);
        f[4] = (short)f2bf(hi.x); f[5] = (short)f2bf(hi.y);
        f[6] = (short)f2bf(hi.z); f[7] = (short)f2bf(hi.w);
        hf[kt] = f;
    }
    f32x4 acc2 = {0.f, 0.f, 0.f, 0.f};
    acc2 = __builtin_amdgcn_mfma_f32_16x16x32_bf16(hf[0], w2f[0], acc2, 0, 0, 0);
    acc2 = __builtin_amdgcn_mfma_f32_16x16x32_bf16(hf[1], w2f[1], acc2, 0, 0, 0);
    if (act && col < OUTD) {
        #pragma unroll
        for (int jr = 0; jr < 4; ++jr) {
            int node = base + 4 * kg + jr;
            if (node < N) outp[(size_t)node * OUTD + col] = sigmoidf_(acc2[jr] + b2v);
        }
    }
}

// ---- mean-pool numerator over bf16 h; graph bounds via in-kernel binary search ----
__global__ void pool_kernel(const unsigned short* __restrict__ hb,
                            const int* __restrict__ batch, int N,
                            float* __restrict__ gemb) {
    int g = blockIdx.x / PSPLIT;
    int part = blockIdx.x % PSPLIT;
    int s = lbound_(batch, N, g);
    int e = lbound_(batch, N, g + 1);
    int tid = threadIdx.x;
    int hc = tid & 63, nl = tid >> 6;
    float sum = 0.0f;
    for (int n = s + part * 4 + nl; n < e; n += PSPLIT * 4)
        sum += bf2f(hb[(size_t)n * HH + hc]);
    __shared__ float red[4][HH];
    red[nl][hc] = sum;
    __syncthreads();
    if (nl == 0) {
        float v = red[0][hc] + red[1][hc] + red[2][hc] + red[3][hc];
        atomicAdd(&gemb[g * HH + hc], v);
    }
}

// ---- optimal head ----
__global__ void optimal_kernel(const float* __restrict__ gemb,
                               const int* __restrict__ batch, int N,
                               const float* __restrict__ Wopt,
                               const float* __restrict__ bopt,
                               float* __restrict__ out2) {
    int g = blockIdx.x;
    int d = threadIdx.x;
    int s = lbound_(batch, N, g);
    int e = lbound_(batch, N, g + 1);
    float c = fmaxf((float)(e - s), 1.0f);
    float v = gemb[g * HH + d] / c * Wopt[d];
    #pragma unroll
    for (int off = 32; off > 0; off >>= 1) v += __shfl_down(v, off);
    if (d == 0) out2[g] = 1.0f / (1.0f + __expf(-(v + bopt[0])));
}

extern "C" void kernel_launch(void* const* d_in, const int* in_sizes, int n_in,
                              void* d_out, int out_size, void* d_ws, size_t ws_size,
                              hipStream_t stream) {
    const float* x     = (const float*)d_in[0];
    const int*   ei    = (const int*)d_in[1];
    const float* ea    = (const float*)d_in[2];
    const int*   batch = (const int*)d_in[3];
    const float* W1    = (const float*)d_in[4];
    const float* b1    = (const float*)d_in[5];
    const float* W2    = (const float*)d_in[6];
    const float* b2    = (const float*)d_in[7];
    const float* Wopt  = (const float*)d_in[8];
    const float* bopt  = (const float*)d_in[9];

    int N = in_sizes[0] / DD;
    int E = in_sizes[2];
    int nbins = (N + 255) >> 8;        // 391 for N=100000 (must be <= NB=512)

    float* out  = (float*)d_out;               // [N, 8]
    float* out2 = out + (size_t)N * OUTD;      // [G]

    // ws: dis[N] | colstart[N] | colcnt[N] | gemb | gcur[NB] | scur[NB] |
    //     dreg[nbins*CAPD]int2 | sreg[nbins*CAPD]u8 | xbf[N*64]u16 | axb[N*32]u32 | hb[N*64]u16
    char* p = (char*)d_ws;
    float* dis      = (float*)p;  p += (size_t)N * 4;
    int*   colstart = (int*)p;    p += (size_t)N * 4;
    int*   colcnt   = (int*)p;    p += (size_t)N * 4;
    float* gemb     = (float*)p;  p += (size_t)NG * HH * 4;
    int*   gcur     = (int*)p;    p += (size_t)NB * 4;
    int*   scur     = (int*)p;    p += (size_t)NB * 4;
    uintptr_t up = (uintptr_t)p; up = (up + 15) & ~(uintptr_t)15; p = (char*)up;
    int2* dreg = (int2*)p;        p += (size_t)nbins * CAPD * 8;
    unsigned char* sreg = (unsigned char*)p; p += (size_t)nbins * CAPD;
    up = (uintptr_t)p; up = (up + 15) & ~(uintptr_t)15; p = (char*)up;
    unsigned short* xbf = (unsigned short*)p; p += (size_t)N * DD * 2;
    unsigned* axb = (unsigned*)p; p += (size_t)N * (DD / 2) * 4;
    unsigned short* hb  = (unsigned short*)p;

    int n8 = N * DD / 8;
    int nbin = (E + BIN_CHUNK - 1) / BIN_CHUNK;
    int nxc = (n8 + BT - 1) / BT;

    hipMemsetAsync(gcur, 0, (size_t)NB * 8, stream);            // gcur + scur (adjacent)
    hipMemsetAsync(gemb, 0, (size_t)NG * HH * 4, stream);

    bin_xcvt_kernel<<<nbin + nxc, BT, 0, stream>>>(ei, ea, gcur, scur, dreg, sreg,
                                                   E, nbin,
                                                   (const float4*)x, (uint4*)xbf, n8);
    deg_kernel<<<nbins, 256, 0, stream>>>(sreg, scur, dis, N);
    csr_kernel<<<nbins, 256, 0, stream>>>(dreg, gcur, dis, colstart, colcnt, N);

    gather_kernel<<<(N + 7) / 8, 256, 0, stream>>>(dreg, colstart, colcnt, dis, xbf, axb, N);

    int ngrp = (N + 15) / 16;
    head_kernel<<<(ngrp + 3) / 4, 256, 0, stream>>>((const unsigned short*)axb,
                                                    W1, b1, W2, b2, hb, out, N);

    pool_kernel<<<NG * PSPLIT, 256, 0, stream>>>(hb, batch, N, gemb);
    optimal_kernel<<<NG, 64, 0, stream>>>(gemb, batch, N, Wopt, bopt, out2);
}

// Round 11
// 128.142 us; speedup vs baseline: 1.4728x; 1.0427x over previous
//
#include <hip/hip_runtime.h>
#include <math.h>
#include <stdint.h>

#define DD 64      // input dim
#define HH 64      // hidden dim
#define OUTD 8     // output dim
#define NG 128     // num graphs
#define PSPLIT 8   // partial blocks per graph in pooling
#define NB 512     // max bins; used bins = ceil(N/256)
#define RSH 8      // range = 256
#define RMSK 255
#define CAPD 3072  // per-bin record capacity (mean 2560, guarded)
#define BIN_CHUNK 4096
#define BT 1024    // bin block threads

typedef short short8 __attribute__((ext_vector_type(8)));
typedef float f32x4 __attribute__((ext_vector_type(4)));

__device__ __forceinline__ float sigmoidf_(float v) { return 1.0f / (1.0f + __expf(-v)); }
__device__ __forceinline__ unsigned short f2bf(float f) {
    unsigned u = __float_as_uint(f);
    unsigned r = u + 0x7FFFu + ((u >> 16) & 1u);
    return (unsigned short)(r >> 16);
}
__device__ __forceinline__ float bf2f(unsigned short b) {
    return __uint_as_float(((unsigned)b) << 16);
}
__device__ __forceinline__ float bflo(unsigned q) { return __uint_as_float(q << 16); }
__device__ __forceinline__ float bfhi(unsigned q) { return __uint_as_float(q & 0xFFFF0000u); }

__device__ __forceinline__ int lbound_(const int* __restrict__ batch, int N, int g) {
    int lo = 0, hi = N;
    while (lo < hi) { int m = (lo + hi) >> 1; if (batch[m] < g) lo = m + 1; else hi = m; }
    return lo;
}

// ---- tiny init: zero bin cursors (replaces pathological fillBuffer dispatches) ----
__global__ void init_kernel(int* cur2) {
    cur2[threadIdx.x] = 0;          // 1024 threads = 2*NB ints
}

// ---- phase 1: bin edges by dest (8B recs) + sources (1B recs); tail blocks do x->bf16 ----
__global__ __launch_bounds__(BT)
void bin_xcvt_kernel(const int* __restrict__ ei, const float* __restrict__ ea,
                     int* gcur, int* scur, int2* __restrict__ dreg,
                     unsigned char* __restrict__ sreg, int E, int nbin,
                     const float4* __restrict__ x4, uint4* __restrict__ xbf, int n8) {
    if (blockIdx.x >= nbin) {
        int i = (blockIdx.x - nbin) * BT + threadIdx.x;
        if (i < n8) {
            float4 a = x4[i * 2], b = x4[i * 2 + 1];
            uint4 o;
            o.x = (unsigned)f2bf(a.x) | ((unsigned)f2bf(a.y) << 16);
            o.y = (unsigned)f2bf(a.z) | ((unsigned)f2bf(a.w) << 16);
            o.z = (unsigned)f2bf(b.x) | ((unsigned)f2bf(b.y) << 16);
            o.w = (unsigned)f2bf(b.z) | ((unsigned)f2bf(b.w) << 16);
            xbf[i] = o;
        }
        return;
    }
    __shared__ int dcnt[NB], scnt[NB], dbase[NB], sbase[NB];
    int t = threadIdx.x;
    for (int j = t; j < NB; j += BT) { dcnt[j] = 0; scnt[j] = 0; }
    __syncthreads();
    int e0 = blockIdx.x * BIN_CHUNK;
    int lim = min(BIN_CHUNK, E - e0);
    int rv0 = 0, rv1 = 0, rv2 = 0, rv3 = 0;
    int cv0 = 0, cv1 = 0, cv2 = 0, cv3 = 0;
    float av0 = 0, av1 = 0, av2 = 0, av3 = 0;
    {
        int i;
        i = t;            if (i < lim) { rv0 = ei[e0+i]; cv0 = ei[E+e0+i]; av0 = ea[e0+i];
                                         atomicAdd(&dcnt[cv0 >> RSH], 1); atomicAdd(&scnt[rv0 >> RSH], 1); }
        i = t + BT;       if (i < lim) { rv1 = ei[e0+i]; cv1 = ei[E+e0+i]; av1 = ea[e0+i];
                                         atomicAdd(&dcnt[cv1 >> RSH], 1); atomicAdd(&scnt[rv1 >> RSH], 1); }
        i = t + 2 * BT;   if (i < lim) { rv2 = ei[e0+i]; cv2 = ei[E+e0+i]; av2 = ea[e0+i];
                                         atomicAdd(&dcnt[cv2 >> RSH], 1); atomicAdd(&scnt[rv2 >> RSH], 1); }
        i = t + 3 * BT;   if (i < lim) { rv3 = ei[e0+i]; cv3 = ei[E+e0+i]; av3 = ea[e0+i];
                                         atomicAdd(&dcnt[cv3 >> RSH], 1); atomicAdd(&scnt[rv3 >> RSH], 1); }
    }
    __syncthreads();
    for (int j = t; j < NB; j += BT) {
        int dc = dcnt[j], sc = scnt[j];
        dbase[j] = dc ? atomicAdd(&gcur[j], dc) : 0;
        sbase[j] = sc ? atomicAdd(&scur[j], sc) : 0;
        dcnt[j] = 0; scnt[j] = 0;
    }
    __syncthreads();
    #define EMIT(RR, CC, AA, II) do { \
        if ((II) < lim) { \
            int b_ = (CC) >> RSH, cl_ = (CC) & RMSK; \
            int pos_ = dbase[b_] + atomicAdd(&dcnt[b_], 1); \
            if (pos_ < CAPD) dreg[(size_t)b_ * CAPD + pos_] = make_int2((RR) | (cl_ << 20), __float_as_int(AA)); \
            int sb_ = (RR) >> RSH; \
            int sp_ = sbase[sb_] + atomicAdd(&scnt[sb_], 1); \
            if (sp_ < CAPD) sreg[(size_t)sb_ * CAPD + sp_] = (unsigned char)((RR) & RMSK); \
        } } while (0)
    EMIT(rv0, cv0, av0, t);
    EMIT(rv1, cv1, av1, t + BT);
    EMIT(rv2, cv2, av2, t + 2 * BT);
    EMIT(rv3, cv3, av3, t + 3 * BT);
    #undef EMIT
}

// ---- phase 2a: per-bin source count -> dis = rsqrt(1 + outdeg) ----
__global__ __launch_bounds__(256)
void deg_kernel(const unsigned char* __restrict__ sreg, const int* __restrict__ scur,
                float* __restrict__ dis, int N) {
    __shared__ int cnt[256];
    int t = threadIdx.x, b = blockIdx.x;
    cnt[t] = 0;
    __syncthreads();
    int n = min(scur[b], CAPD);
    const unsigned char* p = sreg + (size_t)b * CAPD;
    for (int i = t; i < n; i += 256) atomicAdd(&cnt[p[i]], 1);
    __syncthreads();
    int node = (b << RSH) + t;
    if (node < N) dis[node] = rsqrtf(1.0f + (float)cnt[t]);
}

// ---- phase 2b: per-bin exact CSR + pre-multiplied coef ----
__global__ __launch_bounds__(256)
void csr_kernel(int2* __restrict__ dreg, const int* __restrict__ gcur,
                const float* __restrict__ dis,
                int* __restrict__ colstart, int* __restrict__ colcnt, int N) {
    __shared__ int2 recs[CAPD];
    __shared__ int cnt[256], offs_s[256], sc[256];
    int t = threadIdx.x, b = blockIdx.x;
    int n = min(gcur[b], CAPD);
    size_t base = (size_t)b * CAPD;
    for (int i = t; i < n; i += 256) recs[i] = dreg[base + i];
    cnt[t] = 0;
    __syncthreads();
    for (int i = t; i < n; i += 256) atomicAdd(&cnt[recs[i].x >> 20], 1);
    __syncthreads();
    int my = cnt[t];
    sc[t] = my;
    __syncthreads();
    for (int off = 1; off < 256; off <<= 1) {
        int v = (t >= off) ? sc[t - off] : 0;
        __syncthreads();
        sc[t] += v;
        __syncthreads();
    }
    int ex = sc[t] - my;
    offs_s[t] = ex;
    int node = (b << RSH) + t;
    if (node < N) { colstart[node] = (int)(base + ex); colcnt[node] = my; }
    cnt[t] = 0;
    __syncthreads();
    for (int i = t; i < n; i += 256) {
        int2 rc = recs[i];
        int cl = rc.x >> 20;
        int r = rc.x & 0xFFFFF;
        float coef = __int_as_float(rc.y) * dis[r] * dis[(b << RSH) + cl];
        int pos = offs_s[cl] + atomicAdd(&cnt[cl], 1);
        dreg[base + pos] = make_int2(r, __float_as_int(coef));
    }
}

// ---- gather: 4 nodes per wave (16 lanes/node, 4 bf16/lane via uint2) ----
__global__ __launch_bounds__(256)
void gather_kernel(const int2* __restrict__ recs,
                   const int* __restrict__ colstart, const int* __restrict__ colcnt,
                   const float* __restrict__ dis,
                   const unsigned short* __restrict__ xbf,
                   unsigned* __restrict__ axb, int N) {
    int wid = blockIdx.x * 4 + (threadIdx.x >> 6);
    int l = threadIdx.x & 63;
    int q = l >> 4;           // node slot 0..3
    int d4 = l & 15;          // dims 4*d4 .. 4*d4+3
    int node = wid * 4 + q;
    bool v = node < N;
    float s = v ? dis[node] : 0.f;
    uint2 xv = v ? *(const uint2*)(xbf + (size_t)node * DD + 4 * d4) : make_uint2(0u, 0u);
    float s2 = s * s;
    float a0 = s2 * bflo(xv.x), a1 = s2 * bfhi(xv.x);
    float a2 = s2 * bflo(xv.y), a3 = s2 * bfhi(xv.y);
    float b0 = 0.f, b1 = 0.f, b2 = 0.f, b3 = 0.f;
    int cnt = v ? colcnt[node] : 0;
    const int2* p = recs + (v ? colstart[node] : 0);
    int k = 0;
    for (; k + 2 <= cnt; k += 2) {
        int2 r0 = p[k], r1 = p[k + 1];
        uint2 q0 = *(const uint2*)(xbf + (size_t)r0.x * DD + 4 * d4);
        uint2 q1 = *(const uint2*)(xbf + (size_t)r1.x * DD + 4 * d4);
        float c0 = __int_as_float(r0.y), c1 = __int_as_float(r1.y);
        a0 += c0 * bflo(q0.x); a1 += c0 * bfhi(q0.x);
        a2 += c0 * bflo(q0.y); a3 += c0 * bfhi(q0.y);
        b0 += c1 * bflo(q1.x); b1 += c1 * bfhi(q1.x);
        b2 += c1 * bflo(q1.y); b3 += c1 * bfhi(q1.y);
    }
    if (k < cnt) {
        int2 r0 = p[k];
        uint2 q0 = *(const uint2*)(xbf + (size_t)r0.x * DD + 4 * d4);
        float c0 = __int_as_float(r0.y);
        a0 += c0 * bflo(q0.x); a1 += c0 * bfhi(q0.x);
        a2 += c0 * bflo(q0.y); a3 += c0 * bfhi(q0.y);
    }
    if (v) {
        uint2 o;
        o.x = (unsigned)f2bf(a0 + b0) | ((unsigned)f2bf(a1 + b1) << 16);
        o.y = (unsigned)f2bf(a2 + b2) | ((unsigned)f2bf(a3 + b3) << 16);
        *(uint2*)(axb + (size_t)node * (DD / 2) + 2 * d4) = o;
    }
}

// ---- MFMA head: A-frags direct from bf16 aggr; h via LDS transpose; out + hb stores ----
__global__ __launch_bounds__(256)
void head_kernel(const unsigned short* __restrict__ axb,
                 const float* __restrict__ W1, const float* __restrict__ b1,
                 const float* __restrict__ W2, const float* __restrict__ b2,
                 unsigned short* __restrict__ hb, float* __restrict__ outp, int N) {
    __shared__ __align__(16) float htile[4][16][68];
    int tid = threadIdx.x;
    int l = tid & 63, w = tid >> 6;
    int col = l & 15, kg = l >> 4;
    int half = l >> 5, d2 = l & 31;

    short8 w1f[4][2];
    #pragma unroll
    for (int ct = 0; ct < 4; ++ct)
        #pragma unroll
        for (int kt = 0; kt < 2; ++kt) {
            const float* src = W1 + (16 * ct + col) * DD + 32 * kt + 8 * kg;
            short8 f;
            #pragma unroll
            for (int j = 0; j < 8; ++j) f[j] = (short)f2bf(src[j]);
            w1f[ct][kt] = f;
        }
    short8 w2f[2];
    #pragma unroll
    for (int kt = 0; kt < 2; ++kt) {
        short8 f;
        #pragma unroll
        for (int j = 0; j < 8; ++j)
            f[j] = (col < OUTD) ? (short)f2bf(W2[col * HH + 32 * kt + 8 * kg + j]) : (short)0;
        w2f[kt] = f;
    }
    float b1v[4];
    #pragma unroll
    for (int ct = 0; ct < 4; ++ct) b1v[ct] = b1[16 * ct + col];
    float b2v = (col < OUTD) ? b2[col] : 0.f;

    int ngrp = (N + 15) >> 4;
    int g = blockIdx.x * 4 + w;
    bool act = g < ngrp;
    int base = act ? g * 16 : 0;
    int rr = min(base + col, N - 1);

    short8 af[2];
    #pragma unroll
    for (int kt = 0; kt < 2; ++kt)
        af[kt] = *(const short8*)(axb + (size_t)rr * DD + 32 * kt + 8 * kg);

    #pragma unroll
    for (int ct = 0; ct < 4; ++ct) {
        f32x4 acc = {0.f, 0.f, 0.f, 0.f};
        acc = __builtin_amdgcn_mfma_f32_16x16x32_bf16(af[0], w1f[ct][0], acc, 0, 0, 0);
        acc = __builtin_amdgcn_mfma_f32_16x16x32_bf16(af[1], w1f[ct][1], acc, 0, 0, 0);
        #pragma unroll
        for (int jr = 0; jr < 4; ++jr) {
            float v = acc[jr] + b1v[ct];
            float ez = __expf(2.f * v);
            htile[w][4 * kg + jr][16 * ct + col] = (ez - 1.f) / (ez + 1.f);
        }
    }
    __syncthreads();

    #pragma unroll
    for (int it = 0; it < 8; ++it) {
        int node = base + 2 * it + half;
        if (act && node < N) {
            float h0 = htile[w][2 * it + half][2 * d2];
            float h1 = htile[w][2 * it + half][2 * d2 + 1];
            *(unsigned*)(hb + (size_t)node * HH + 2 * d2) =
                (unsigned)f2bf(h0) | ((unsigned)f2bf(h1) << 16);
        }
    }

    short8 hf[2];
    #pragma unroll
    for (int kt = 0; kt < 2; ++kt) {
        const float* src = &htile[w][col][32 * kt + 8 * kg];
        float4 lo = *(const float4*)src;
        float4 hi = *(const float4*)(src + 4);
        short8 f;
        f[0] = (short)f2bf(lo.x); f[1] = (short)f2bf(lo.y);
        f[2] = (short)f2bf(lo.z); f[3] = (short)f2bf(lo.w);
        f[4] = (short)f2bf(hi.x); f[5] = (short)f2bf(hi.y);
        f[6] = (short)f2bf(hi.z); f[7] = (short)f2bf(hi.w);
        hf[kt] = f;
    }
    f32x4 acc2 = {0.f, 0.f, 0.f, 0.f};
    acc2 = __builtin_amdgcn_mfma_f32_16x16x32_bf16(hf[0], w2f[0], acc2, 0, 0, 0);
    acc2 = __builtin_amdgcn_mfma_f32_16x16x32_bf16(hf[1], w2f[1], acc2, 0, 0, 0);
    if (act && col < OUTD) {
        #pragma unroll
        for (int jr = 0; jr < 4; ++jr) {
            int node = base + 4 * kg + jr;
            if (node < N) outp[(size_t)node * OUTD + col] = sigmoidf_(acc2[jr] + b2v);
        }
    }
}

// ---- mean-pool partials: unconditional writes, no atomics, no zero-init ----
__global__ void pool_kernel(const unsigned short* __restrict__ hb,
                            const int* __restrict__ batch, int N,
                            float* __restrict__ pp) {
    int g = blockIdx.x / PSPLIT;
    int part = blockIdx.x % PSPLIT;
    int s = lbound_(batch, N, g);
    int e = lbound_(batch, N, g + 1);
    int tid = threadIdx.x;
    int hc = tid & 63, nl = tid >> 6;
    float sum = 0.0f;
    for (int n = s + part * 4 + nl; n < e; n += PSPLIT * 4)
        sum += bf2f(hb[(size_t)n * HH + hc]);
    __shared__ float red[4][HH];
    red[nl][hc] = sum;
    __syncthreads();
    if (nl == 0)
        pp[((size_t)g * PSPLIT + part) * HH + hc] =
            red[0][hc] + red[1][hc] + red[2][hc] + red[3][hc];
}

// ---- optimal head: sum partials, dot with Wopt ----
__global__ void optimal_kernel(const float* __restrict__ pp,
                               const int* __restrict__ batch, int N,
                               const float* __restrict__ Wopt,
                               const float* __restrict__ bopt,
                               float* __restrict__ out2) {
    int g = blockIdx.x;
    int d = threadIdx.x;
    int s = lbound_(batch, N, g);
    int e = lbound_(batch, N, g + 1);
    float c = fmaxf((float)(e - s), 1.0f);
    float acc = 0.f;
    #pragma unroll
    for (int part = 0; part < PSPLIT; ++part)
        acc += pp[((size_t)g * PSPLIT + part) * HH + d];
    float v = acc / c * Wopt[d];
    #pragma unroll
    for (int off = 32; off > 0; off >>= 1) v += __shfl_down(v, off);
    if (d == 0) out2[g] = 1.0f / (1.0f + __expf(-(v + bopt[0])));
}

extern "C" void kernel_launch(void* const* d_in, const int* in_sizes, int n_in,
                              void* d_out, int out_size, void* d_ws, size_t ws_size,
                              hipStream_t stream) {
    const float* x     = (const float*)d_in[0];
    const int*   ei    = (const int*)d_in[1];
    const float* ea    = (const float*)d_in[2];
    const int*   batch = (const int*)d_in[3];
    const float* W1    = (const float*)d_in[4];
    const float* b1    = (const float*)d_in[5];
    const float* W2    = (const float*)d_in[6];
    const float* b2    = (const float*)d_in[7];
    const float* Wopt  = (const float*)d_in[8];
    const float* bopt  = (const float*)d_in[9];

    int N = in_sizes[0] / DD;
    int E = in_sizes[2];
    int nbins = (N + 255) >> 8;        // 391 for N=100000 (<= NB=512)

    float* out  = (float*)d_out;               // [N, 8]
    float* out2 = out + (size_t)N * OUTD;      // [G]

    // ws: dis[N] | colstart[N] | colcnt[N] | pp[NG*PSPLIT*HH] | gcur[NB] | scur[NB] |
    //     dreg[nbins*CAPD]int2 | sreg[nbins*CAPD]u8 | xbf[N*64]u16 | axb[N*32]u32 | hb[N*64]u16
    char* p = (char*)d_ws;
    float* dis      = (float*)p;  p += (size_t)N * 4;
    int*   colstart = (int*)p;    p += (size_t)N * 4;
    int*   colcnt   = (int*)p;    p += (size_t)N * 4;
    float* pp       = (float*)p;  p += (size_t)NG * PSPLIT * HH * 4;
    int*   gcur     = (int*)p;    p += (size_t)NB * 4;
    int*   scur     = (int*)p;    p += (size_t)NB * 4;
    uintptr_t up = (uintptr_t)p; up = (up + 15) & ~(uintptr_t)15; p = (char*)up;
    int2* dreg = (int2*)p;        p += (size_t)nbins * CAPD * 8;
    unsigned char* sreg = (unsigned char*)p; p += (size_t)nbins * CAPD;
    up = (uintptr_t)p; up = (up + 15) & ~(uintptr_t)15; p = (char*)up;
    unsigned short* xbf = (unsigned short*)p; p += (size_t)N * DD * 2;
    unsigned* axb = (unsigned*)p; p += (size_t)N * (DD / 2) * 4;
    unsigned short* hb  = (unsigned short*)p;

    int n8 = N * DD / 8;
    int nbin = (E + BIN_CHUNK - 1) / BIN_CHUNK;
    int nxc = (n8 + BT - 1) / BT;

    init_kernel<<<1, 2 * NB, 0, stream>>>(gcur);   // gcur+scur adjacent
    bin_xcvt_kernel<<<nbin + nxc, BT, 0, stream>>>(ei, ea, gcur, scur, dreg, sreg,
                                                   E, nbin,
                                                   (const float4*)x, (uint4*)xbf, n8);
    deg_kernel<<<nbins, 256, 0, stream>>>(sreg, scur, dis, N);
    csr_kernel<<<nbins, 256, 0, stream>>>(dreg, gcur, dis, colstart, colcnt, N);

    gather_kernel<<<(N + 15) / 16, 256, 0, stream>>>(dreg, colstart, colcnt, dis, xbf, axb, N);

    int ngrp = (N + 15) / 16;
    head_kernel<<<(ngrp + 3) / 4, 256, 0, stream>>>((const unsigned short*)axb,
                                                    W1, b1, W2, b2, hb, out, N);

    pool_kernel<<<NG * PSPLIT, 256, 0, stream>>>(hb, batch, N, pp);
    optimal_kernel<<<NG, 64, 0, stream>>>(pp, batch, N, Wopt, bopt, out2);
}

// Round 12
// 124.913 us; speedup vs baseline: 1.5109x; 1.0258x over previous
//
#include <hip/hip_runtime.h>
#include <math.h>
#include <stdint.h>

#define DD 64      // input dim
#define HH 64      // hidden dim
#define OUTD 8     // output dim
#define NG 128     // num graphs
#define PSPLIT 8   // partial blocks per graph in pooling
#define NB 512     // max bins; used bins = ceil(N/256)
#define RSH 8      // range = 256
#define RMSK 255
#define CAPD 3072  // per-bin record capacity (mean 2560, guarded)
#define BIN_CHUNK 4096
#define BT 1024    // bin block threads

typedef short short8 __attribute__((ext_vector_type(8)));
typedef float f32x4 __attribute__((ext_vector_type(4)));

__device__ __forceinline__ float sigmoidf_(float v) { return 1.0f / (1.0f + __expf(-v)); }
__device__ __forceinline__ unsigned short f2bf(float f) {
    unsigned u = __float_as_uint(f);
    unsigned r = u + 0x7FFFu + ((u >> 16) & 1u);
    return (unsigned short)(r >> 16);
}
__device__ __forceinline__ float bf2f(unsigned short b) {
    return __uint_as_float(((unsigned)b) << 16);
}
__device__ __forceinline__ float bflo(unsigned q) { return __uint_as_float(q << 16); }
__device__ __forceinline__ float bfhi(unsigned q) { return __uint_as_float(q & 0xFFFF0000u); }

__device__ __forceinline__ int lbound_(const int* __restrict__ batch, int N, int g) {
    int lo = 0, hi = N;
    while (lo < hi) { int m = (lo + hi) >> 1; if (batch[m] < g) lo = m + 1; else hi = m; }
    return lo;
}

// ---- tiny init: zero bin cursors ----
__global__ void init_kernel(int* cur2) {
    cur2[threadIdx.x] = 0;          // 1024 threads = 2*NB ints
}

// ---- phase 1: bin edges by dest (8B recs) + sources (1B recs); tail blocks do x->bf16 ----
__global__ __launch_bounds__(BT)
void bin_xcvt_kernel(const int* __restrict__ ei, const float* __restrict__ ea,
                     int* gcur, int* scur, int2* __restrict__ dreg,
                     unsigned char* __restrict__ sreg, int E, int nbin,
                     const float4* __restrict__ x4, uint4* __restrict__ xbf, int n8) {
    if (blockIdx.x >= nbin) {
        int i = (blockIdx.x - nbin) * BT + threadIdx.x;
        if (i < n8) {
            float4 a = x4[i * 2], b = x4[i * 2 + 1];
            uint4 o;
            o.x = (unsigned)f2bf(a.x) | ((unsigned)f2bf(a.y) << 16);
            o.y = (unsigned)f2bf(a.z) | ((unsigned)f2bf(a.w) << 16);
            o.z = (unsigned)f2bf(b.x) | ((unsigned)f2bf(b.y) << 16);
            o.w = (unsigned)f2bf(b.z) | ((unsigned)f2bf(b.w) << 16);
            xbf[i] = o;
        }
        return;
    }
    __shared__ int dcnt[NB], scnt[NB], dbase[NB], sbase[NB];
    int t = threadIdx.x;
    for (int j = t; j < NB; j += BT) { dcnt[j] = 0; scnt[j] = 0; }
    __syncthreads();
    int e0 = blockIdx.x * BIN_CHUNK;
    int lim = min(BIN_CHUNK, E - e0);
    int rv0 = 0, rv1 = 0, rv2 = 0, rv3 = 0;
    int cv0 = 0, cv1 = 0, cv2 = 0, cv3 = 0;
    float av0 = 0, av1 = 0, av2 = 0, av3 = 0;
    {
        int i;
        i = t;            if (i < lim) { rv0 = ei[e0+i]; cv0 = ei[E+e0+i]; av0 = ea[e0+i];
                                         atomicAdd(&dcnt[cv0 >> RSH], 1); atomicAdd(&scnt[rv0 >> RSH], 1); }
        i = t + BT;       if (i < lim) { rv1 = ei[e0+i]; cv1 = ei[E+e0+i]; av1 = ea[e0+i];
                                         atomicAdd(&dcnt[cv1 >> RSH], 1); atomicAdd(&scnt[rv1 >> RSH], 1); }
        i = t + 2 * BT;   if (i < lim) { rv2 = ei[e0+i]; cv2 = ei[E+e0+i]; av2 = ea[e0+i];
                                         atomicAdd(&dcnt[cv2 >> RSH], 1); atomicAdd(&scnt[rv2 >> RSH], 1); }
        i = t + 3 * BT;   if (i < lim) { rv3 = ei[e0+i]; cv3 = ei[E+e0+i]; av3 = ea[e0+i];
                                         atomicAdd(&dcnt[cv3 >> RSH], 1); atomicAdd(&scnt[rv3 >> RSH], 1); }
    }
    __syncthreads();
    for (int j = t; j < NB; j += BT) {
        int dc = dcnt[j], sc = scnt[j];
        dbase[j] = dc ? atomicAdd(&gcur[j], dc) : 0;
        sbase[j] = sc ? atomicAdd(&scur[j], sc) : 0;
        dcnt[j] = 0; scnt[j] = 0;
    }
    __syncthreads();
    #define EMIT(RR, CC, AA, II) do { \
        if ((II) < lim) { \
            int b_ = (CC) >> RSH, cl_ = (CC) & RMSK; \
            int pos_ = dbase[b_] + atomicAdd(&dcnt[b_], 1); \
            if (pos_ < CAPD) dreg[(size_t)b_ * CAPD + pos_] = make_int2((RR) | (cl_ << 20), __float_as_int(AA)); \
            int sb_ = (RR) >> RSH; \
            int sp_ = sbase[sb_] + atomicAdd(&scnt[sb_], 1); \
            if (sp_ < CAPD) sreg[(size_t)sb_ * CAPD + sp_] = (unsigned char)((RR) & RMSK); \
        } } while (0)
    EMIT(rv0, cv0, av0, t);
    EMIT(rv1, cv1, av1, t + BT);
    EMIT(rv2, cv2, av2, t + 2 * BT);
    EMIT(rv3, cv3, av3, t + 3 * BT);
    #undef EMIT
}

// ---- phase 2a: per-bin source count -> dis = rsqrt(1 + outdeg) ----
__global__ __launch_bounds__(256)
void deg_kernel(const unsigned char* __restrict__ sreg, const int* __restrict__ scur,
                float* __restrict__ dis, int N) {
    __shared__ int cnt[256];
    int t = threadIdx.x, b = blockIdx.x;
    cnt[t] = 0;
    __syncthreads();
    int n = min(scur[b], CAPD);
    const unsigned char* p = sreg + (size_t)b * CAPD;
    for (int i = t; i < n; i += 256) atomicAdd(&cnt[p[i]], 1);
    __syncthreads();
    int node = (b << RSH) + t;
    if (node < N) dis[node] = rsqrtf(1.0f + (float)cnt[t]);
}

// ---- phase 2b: per-bin exact CSR + pre-multiplied coef ----
__global__ __launch_bounds__(256)
void csr_kernel(int2* __restrict__ dreg, const int* __restrict__ gcur,
                const float* __restrict__ dis,
                int* __restrict__ colstart, int* __restrict__ colcnt, int N) {
    __shared__ int2 recs[CAPD];
    __shared__ int cnt[256], offs_s[256], sc[256];
    int t = threadIdx.x, b = blockIdx.x;
    int n = min(gcur[b], CAPD);
    size_t base = (size_t)b * CAPD;
    for (int i = t; i < n; i += 256) recs[i] = dreg[base + i];
    cnt[t] = 0;
    __syncthreads();
    for (int i = t; i < n; i += 256) atomicAdd(&cnt[recs[i].x >> 20], 1);
    __syncthreads();
    int my = cnt[t];
    sc[t] = my;
    __syncthreads();
    for (int off = 1; off < 256; off <<= 1) {
        int v = (t >= off) ? sc[t - off] : 0;
        __syncthreads();
        sc[t] += v;
        __syncthreads();
    }
    int ex = sc[t] - my;
    offs_s[t] = ex;
    int node = (b << RSH) + t;
    if (node < N) { colstart[node] = (int)(base + ex); colcnt[node] = my; }
    cnt[t] = 0;
    __syncthreads();
    for (int i = t; i < n; i += 256) {
        int2 rc = recs[i];
        int cl = rc.x >> 20;
        int r = rc.x & 0xFFFFF;
        float coef = __int_as_float(rc.y) * dis[r] * dis[(b << RSH) + cl];
        int pos = offs_s[cl] + atomicAdd(&cnt[cl], 1);
        dreg[base + pos] = make_int2(r, __float_as_int(coef));
    }
}

// ---- fused gather + MFMA head, wave-synchronous (no __syncthreads in loop) ----
// Each wave owns a 16-node group: gather (8 lanes/node, uint4) -> bf16 LDS tile ->
// MFMA GEMM1 + tanh -> bf16 htile -> hb store + MFMA GEMM2 -> out store.
__global__ __launch_bounds__(256, 4)
void ghead_kernel(const int2* __restrict__ recs,
                  const int* __restrict__ colstart, const int* __restrict__ colcnt,
                  const float* __restrict__ dis,
                  const unsigned short* __restrict__ xbf,
                  const float* __restrict__ W1, const float* __restrict__ b1,
                  const float* __restrict__ W2, const float* __restrict__ b2,
                  unsigned short* __restrict__ hb, float* __restrict__ outp, int N) {
    __shared__ __align__(16) unsigned short atile[4][16][72];
    __shared__ __align__(16) unsigned short htile[4][16][72];
    int tid = threadIdx.x;
    int l = tid & 63, w = tid >> 6;
    int col = l & 15, kg = l >> 4;
    int q = l >> 3, d8 = l & 7;          // gather: node sub-slot / dim-block

    // W1/W2 B-frags: B[k][c] = W[c][k]; lane: c = 16*ct+col, k = 32*kt+8*kg+j
    short8 w1f[4][2];
    #pragma unroll
    for (int ct = 0; ct < 4; ++ct)
        #pragma unroll
        for (int kt = 0; kt < 2; ++kt) {
            const float* src = W1 + (16 * ct + col) * DD + 32 * kt + 8 * kg;
            short8 f;
            #pragma unroll
            for (int j = 0; j < 8; ++j) f[j] = (short)f2bf(src[j]);
            w1f[ct][kt] = f;
        }
    short8 w2f[2];
    #pragma unroll
    for (int kt = 0; kt < 2; ++kt) {
        short8 f;
        #pragma unroll
        for (int j = 0; j < 8; ++j)
            f[j] = (col < OUTD) ? (short)f2bf(W2[col * HH + 32 * kt + 8 * kg + j]) : (short)0;
        w2f[kt] = f;
    }
    float b1v[4];
    #pragma unroll
    for (int ct = 0; ct < 4; ++ct) b1v[ct] = b1[16 * ct + col];
    float b2v = (col < OUTD) ? b2[col] : 0.f;

    int ngrp = (N + 15) >> 4;
    for (int grp = blockIdx.x * 4 + w; grp < ngrp; grp += gridDim.x * 4) {
        int base = grp * 16;
        // ---- gather 16 nodes in 2 batches of 8 (8 lanes/node, 8 dims/lane) ----
        #pragma unroll
        for (int it = 0; it < 2; ++it) {
            int node = base + it * 8 + q;
            bool v = node < N;
            float s = v ? dis[node] : 0.f;
            uint4 xv = v ? *(const uint4*)(xbf + (size_t)node * DD + 8 * d8)
                         : make_uint4(0u, 0u, 0u, 0u);
            float s2 = s * s;
            float a0 = s2 * bflo(xv.x), a1 = s2 * bfhi(xv.x);
            float a2 = s2 * bflo(xv.y), a3 = s2 * bfhi(xv.y);
            float a4 = s2 * bflo(xv.z), a5 = s2 * bfhi(xv.z);
            float a6 = s2 * bflo(xv.w), a7 = s2 * bfhi(xv.w);
            int cnt = v ? colcnt[node] : 0;
            const int2* p = recs + (v ? colstart[node] : 0);
            int k = 0;
            for (; k + 2 <= cnt; k += 2) {
                int2 r0 = p[k], r1 = p[k + 1];
                uint4 q0 = *(const uint4*)(xbf + (size_t)r0.x * DD + 8 * d8);
                uint4 q1 = *(const uint4*)(xbf + (size_t)r1.x * DD + 8 * d8);
                float c0 = __int_as_float(r0.y), c1 = __int_as_float(r1.y);
                a0 += c0 * bflo(q0.x); a1 += c0 * bfhi(q0.x);
                a2 += c0 * bflo(q0.y); a3 += c0 * bfhi(q0.y);
                a4 += c0 * bflo(q0.z); a5 += c0 * bfhi(q0.z);
                a6 += c0 * bflo(q0.w); a7 += c0 * bfhi(q0.w);
                a0 += c1 * bflo(q1.x); a1 += c1 * bfhi(q1.x);
                a2 += c1 * bflo(q1.y); a3 += c1 * bfhi(q1.y);
                a4 += c1 * bflo(q1.z); a5 += c1 * bfhi(q1.z);
                a6 += c1 * bflo(q1.w); a7 += c1 * bfhi(q1.w);
            }
            if (k < cnt) {
                int2 r0 = p[k];
                uint4 q0 = *(const uint4*)(xbf + (size_t)r0.x * DD + 8 * d8);
                float c0 = __int_as_float(r0.y);
                a0 += c0 * bflo(q0.x); a1 += c0 * bfhi(q0.x);
                a2 += c0 * bflo(q0.y); a3 += c0 * bfhi(q0.y);
                a4 += c0 * bflo(q0.z); a5 += c0 * bfhi(q0.z);
                a6 += c0 * bflo(q0.w); a7 += c0 * bfhi(q0.w);
            }
            uint4 o;
            o.x = (unsigned)f2bf(a0) | ((unsigned)f2bf(a1) << 16);
            o.y = (unsigned)f2bf(a2) | ((unsigned)f2bf(a3) << 16);
            o.z = (unsigned)f2bf(a4) | ((unsigned)f2bf(a5) << 16);
            o.w = (unsigned)f2bf(a6) | ((unsigned)f2bf(a7) << 16);
            *(uint4*)&atile[w][it * 8 + q][8 * d8] = o;
        }
        // ---- GEMM1 from wave-private LDS tile (wave-sync, no barrier) ----
        short8 af[2];
        #pragma unroll
        for (int kt = 0; kt < 2; ++kt)
            af[kt] = *(const short8*)&atile[w][col][32 * kt + 8 * kg];
        #pragma unroll
        for (int ct = 0; ct < 4; ++ct) {
            f32x4 acc = {0.f, 0.f, 0.f, 0.f};
            acc = __builtin_amdgcn_mfma_f32_16x16x32_bf16(af[0], w1f[ct][0], acc, 0, 0, 0);
            acc = __builtin_amdgcn_mfma_f32_16x16x32_bf16(af[1], w1f[ct][1], acc, 0, 0, 0);
            #pragma unroll
            for (int jr = 0; jr < 4; ++jr) {
                float v = acc[jr] + b1v[ct];
                float ez = __expf(2.f * v);
                htile[w][4 * kg + jr][16 * ct + col] = f2bf((ez - 1.f) / (ez + 1.f));
            }
        }
        // ---- hb store (coalesced uint4 per lane) ----
        #pragma unroll
        for (int it = 0; it < 2; ++it) {
            int node = base + it * 8 + q;
            if (node < N)
                *(uint4*)(hb + (size_t)node * HH + 8 * d8) =
                    *(const uint4*)&htile[w][it * 8 + q][8 * d8];
        }
        // ---- GEMM2 (out head) ----
        short8 hf[2];
        #pragma unroll
        for (int kt = 0; kt < 2; ++kt)
            hf[kt] = *(const short8*)&htile[w][col][32 * kt + 8 * kg];
        f32x4 acc2 = {0.f, 0.f, 0.f, 0.f};
        acc2 = __builtin_amdgcn_mfma_f32_16x16x32_bf16(hf[0], w2f[0], acc2, 0, 0, 0);
        acc2 = __builtin_amdgcn_mfma_f32_16x16x32_bf16(hf[1], w2f[1], acc2, 0, 0, 0);
        if (col < OUTD) {
            #pragma unroll
            for (int jr = 0; jr < 4; ++jr) {
                int node = base + 4 * kg + jr;
                if (node < N) outp[(size_t)node * OUTD + col] = sigmoidf_(acc2[jr] + b2v);
            }
        }
    }
}

// ---- mean-pool partials: unconditional writes, no atomics, no zero-init ----
__global__ void pool_kernel(const unsigned short* __restrict__ hb,
                            const int* __restrict__ batch, int N,
                            float* __restrict__ pp) {
    int g = blockIdx.x / PSPLIT;
    int part = blockIdx.x % PSPLIT;
    int s = lbound_(batch, N, g);
    int e = lbound_(batch, N, g + 1);
    int tid = threadIdx.x;
    int hc = tid & 63, nl = tid >> 6;
    float sum = 0.0f;
    for (int n = s + part * 4 + nl; n < e; n += PSPLIT * 4)
        sum += bf2f(hb[(size_t)n * HH + hc]);
    __shared__ float red[4][HH];
    red[nl][hc] = sum;
    __syncthreads();
    if (nl == 0)
        pp[((size_t)g * PSPLIT + part) * HH + hc] =
            red[0][hc] + red[1][hc] + red[2][hc] + red[3][hc];
}

// ---- optimal head: sum partials, dot with Wopt ----
__global__ void optimal_kernel(const float* __restrict__ pp,
                               const int* __restrict__ batch, int N,
                               const float* __restrict__ Wopt,
                               const float* __restrict__ bopt,
                               float* __restrict__ out2) {
    int g = blockIdx.x;
    int d = threadIdx.x;
    int s = lbound_(batch, N, g);
    int e = lbound_(batch, N, g + 1);
    float c = fmaxf((float)(e - s), 1.0f);
    float acc = 0.f;
    #pragma unroll
    for (int part = 0; part < PSPLIT; ++part)
        acc += pp[((size_t)g * PSPLIT + part) * HH + d];
    float v = acc / c * Wopt[d];
    #pragma unroll
    for (int off = 32; off > 0; off >>= 1) v += __shfl_down(v, off);
    if (d == 0) out2[g] = 1.0f / (1.0f + __expf(-(v + bopt[0])));
}

extern "C" void kernel_launch(void* const* d_in, const int* in_sizes, int n_in,
                              void* d_out, int out_size, void* d_ws, size_t ws_size,
                              hipStream_t stream) {
    const float* x     = (const float*)d_in[0];
    const int*   ei    = (const int*)d_in[1];
    const float* ea    = (const float*)d_in[2];
    const int*   batch = (const int*)d_in[3];
    const float* W1    = (const float*)d_in[4];
    const float* b1    = (const float*)d_in[5];
    const float* W2    = (const float*)d_in[6];
    const float* b2    = (const float*)d_in[7];
    const float* Wopt  = (const float*)d_in[8];
    const float* bopt  = (const float*)d_in[9];

    int N = in_sizes[0] / DD;
    int E = in_sizes[2];
    int nbins = (N + 255) >> 8;        // 391 for N=100000 (<= NB=512)

    float* out  = (float*)d_out;               // [N, 8]
    float* out2 = out + (size_t)N * OUTD;      // [G]

    // ws: dis[N] | colstart[N] | colcnt[N] | pp[NG*PSPLIT*HH] | gcur[NB] | scur[NB] |
    //     dreg[nbins*CAPD]int2 | sreg[nbins*CAPD]u8 | xbf[N*64]u16 | hb[N*64]u16
    char* p = (char*)d_ws;
    float* dis      = (float*)p;  p += (size_t)N * 4;
    int*   colstart = (int*)p;    p += (size_t)N * 4;
    int*   colcnt   = (int*)p;    p += (size_t)N * 4;
    float* pp       = (float*)p;  p += (size_t)NG * PSPLIT * HH * 4;
    int*   gcur     = (int*)p;    p += (size_t)NB * 4;
    int*   scur     = (int*)p;    p += (size_t)NB * 4;
    uintptr_t up = (uintptr_t)p; up = (up + 15) & ~(uintptr_t)15; p = (char*)up;
    int2* dreg = (int2*)p;        p += (size_t)nbins * CAPD * 8;
    unsigned char* sreg = (unsigned char*)p; p += (size_t)nbins * CAPD;
    up = (uintptr_t)p; up = (up + 15) & ~(uintptr_t)15; p = (char*)up;
    unsigned short* xbf = (unsigned short*)p; p += (size_t)N * DD * 2;
    unsigned short* hb  = (unsigned short*)p;

    int n8 = N * DD / 8;
    int nbin = (E + BIN_CHUNK - 1) / BIN_CHUNK;
    int nxc = (n8 + BT - 1) / BT;

    init_kernel<<<1, 2 * NB, 0, stream>>>(gcur);   // gcur+scur adjacent
    bin_xcvt_kernel<<<nbin + nxc, BT, 0, stream>>>(ei, ea, gcur, scur, dreg, sreg,
                                                   E, nbin,
                                                   (const float4*)x, (uint4*)xbf, n8);
    deg_kernel<<<nbins, 256, 0, stream>>>(sreg, scur, dis, N);
    csr_kernel<<<nbins, 256, 0, stream>>>(dreg, gcur, dis, colstart, colcnt, N);

    int ngrp = (N + 15) / 16;
    ghead_kernel<<<(ngrp + 3) / 4, 256, 0, stream>>>(dreg, colstart, colcnt, dis, xbf,
                                                     W1, b1, W2, b2, hb, out, N);

    pool_kernel<<<NG * PSPLIT, 256, 0, stream>>>(hb, batch, N, pp);
    optimal_kernel<<<NG, 64, 0, stream>>>(pp, batch, N, Wopt, bopt, out2);
}

// Round 13
// 117.969 us; speedup vs baseline: 1.5999x; 1.0589x over previous
//
#include <hip/hip_runtime.h>
#include <math.h>
#include <stdint.h>

#define DD 64      // input dim
#define HH 64      // hidden dim
#define OUTD 8     // output dim
#define NG 128     // num graphs
#define PSPLIT 8   // partial blocks per graph in pooling
#define NB 512     // max bins; used bins = ceil(N/256)
#define RSH 8      // range = 256
#define RMSK 255
#define CAPD 3072  // per-bin record capacity (mean 2560, guarded)
#define BIN_CHUNK 4096
#define BT 1024    // bin block threads

typedef short short8 __attribute__((ext_vector_type(8)));
typedef float f32x4 __attribute__((ext_vector_type(4)));

__device__ __forceinline__ float sigmoidf_(float v) { return 1.0f / (1.0f + __expf(-v)); }
__device__ __forceinline__ unsigned short f2bf(float f) {
    unsigned u = __float_as_uint(f);
    unsigned r = u + 0x7FFFu + ((u >> 16) & 1u);
    return (unsigned short)(r >> 16);
}
__device__ __forceinline__ float bf2f(unsigned short b) {
    return __uint_as_float(((unsigned)b) << 16);
}
__device__ __forceinline__ float bflo(unsigned q) { return __uint_as_float(q << 16); }
__device__ __forceinline__ float bfhi(unsigned q) { return __uint_as_float(q & 0xFFFF0000u); }

__device__ __forceinline__ int lbound_(const int* __restrict__ batch, int N, int g) {
    int lo = 0, hi = N;
    while (lo < hi) { int m = (lo + hi) >> 1; if (batch[m] < g) lo = m + 1; else hi = m; }
    return lo;
}

// ---- tiny init: zero bin cursors ----
__global__ void init_kernel(int* cur2) {
    cur2[threadIdx.x] = 0;          // 1024 threads = 2*NB ints
}

// ---- phase 1: bin edges by dest (8B recs) + sources (1B recs); tail blocks do x->bf16 ----
__global__ __launch_bounds__(BT)
void bin_xcvt_kernel(const int* __restrict__ ei, const float* __restrict__ ea,
                     int* gcur, int* scur, int2* __restrict__ dreg,
                     unsigned char* __restrict__ sreg, int E, int nbin,
                     const float4* __restrict__ x4, uint4* __restrict__ xbf, int n8) {
    if (blockIdx.x >= nbin) {
        int i = (blockIdx.x - nbin) * BT + threadIdx.x;
        if (i < n8) {
            float4 a = x4[i * 2], b = x4[i * 2 + 1];
            uint4 o;
            o.x = (unsigned)f2bf(a.x) | ((unsigned)f2bf(a.y) << 16);
            o.y = (unsigned)f2bf(a.z) | ((unsigned)f2bf(a.w) << 16);
            o.z = (unsigned)f2bf(b.x) | ((unsigned)f2bf(b.y) << 16);
            o.w = (unsigned)f2bf(b.z) | ((unsigned)f2bf(b.w) << 16);
            xbf[i] = o;
        }
        return;
    }
    __shared__ int dcnt[NB], scnt[NB], dbase[NB], sbase[NB];
    int t = threadIdx.x;
    for (int j = t; j < NB; j += BT) { dcnt[j] = 0; scnt[j] = 0; }
    __syncthreads();
    int e0 = blockIdx.x * BIN_CHUNK;
    int lim = min(BIN_CHUNK, E - e0);
    int rv0 = 0, rv1 = 0, rv2 = 0, rv3 = 0;
    int cv0 = 0, cv1 = 0, cv2 = 0, cv3 = 0;
    float av0 = 0, av1 = 0, av2 = 0, av3 = 0;
    {
        int i;
        i = t;            if (i < lim) { rv0 = ei[e0+i]; cv0 = ei[E+e0+i]; av0 = ea[e0+i];
                                         atomicAdd(&dcnt[cv0 >> RSH], 1); atomicAdd(&scnt[rv0 >> RSH], 1); }
        i = t + BT;       if (i < lim) { rv1 = ei[e0+i]; cv1 = ei[E+e0+i]; av1 = ea[e0+i];
                                         atomicAdd(&dcnt[cv1 >> RSH], 1); atomicAdd(&scnt[rv1 >> RSH], 1); }
        i = t + 2 * BT;   if (i < lim) { rv2 = ei[e0+i]; cv2 = ei[E+e0+i]; av2 = ea[e0+i];
                                         atomicAdd(&dcnt[cv2 >> RSH], 1); atomicAdd(&scnt[rv2 >> RSH], 1); }
        i = t + 3 * BT;   if (i < lim) { rv3 = ei[e0+i]; cv3 = ei[E+e0+i]; av3 = ea[e0+i];
                                         atomicAdd(&dcnt[cv3 >> RSH], 1); atomicAdd(&scnt[rv3 >> RSH], 1); }
    }
    __syncthreads();
    for (int j = t; j < NB; j += BT) {
        int dc = dcnt[j], sc = scnt[j];
        dbase[j] = dc ? atomicAdd(&gcur[j], dc) : 0;
        sbase[j] = sc ? atomicAdd(&scur[j], sc) : 0;
        dcnt[j] = 0; scnt[j] = 0;
    }
    __syncthreads();
    #define EMIT(RR, CC, AA, II) do { \
        if ((II) < lim) { \
            int b_ = (CC) >> RSH, cl_ = (CC) & RMSK; \
            int pos_ = dbase[b_] + atomicAdd(&dcnt[b_], 1); \
            if (pos_ < CAPD) dreg[(size_t)b_ * CAPD + pos_] = make_int2((RR) | (cl_ << 20), __float_as_int(AA)); \
            int sb_ = (RR) >> RSH; \
            int sp_ = sbase[sb_] + atomicAdd(&scnt[sb_], 1); \
            if (sp_ < CAPD) sreg[(size_t)sb_ * CAPD + sp_] = (unsigned char)((RR) & RMSK); \
        } } while (0)
    EMIT(rv0, cv0, av0, t);
    EMIT(rv1, cv1, av1, t + BT);
    EMIT(rv2, cv2, av2, t + 2 * BT);
    EMIT(rv3, cv3, av3, t + 3 * BT);
    #undef EMIT
}

// ---- phase 2a: per-bin source count -> dis = rsqrt(1 + outdeg) ----
__global__ __launch_bounds__(256)
void deg_kernel(const unsigned char* __restrict__ sreg, const int* __restrict__ scur,
                float* __restrict__ dis, int N) {
    __shared__ int cnt[256];
    int t = threadIdx.x, b = blockIdx.x;
    cnt[t] = 0;
    __syncthreads();
    int n = min(scur[b], CAPD);
    const unsigned char* p = sreg + (size_t)b * CAPD;
    for (int i = t; i < n; i += 256) atomicAdd(&cnt[p[i]], 1);
    __syncthreads();
    int node = (b << RSH) + t;
    if (node < N) dis[node] = rsqrtf(1.0f + (float)cnt[t]);
}

// ---- phase 2b: per-bin exact CSR + pre-multiplied coef ----
__global__ __launch_bounds__(256)
void csr_kernel(int2* __restrict__ dreg, const int* __restrict__ gcur,
                const float* __restrict__ dis,
                int* __restrict__ colstart, int* __restrict__ colcnt, int N) {
    __shared__ int2 recs[CAPD];
    __shared__ int cnt[256], offs_s[256], sc[256];
    int t = threadIdx.x, b = blockIdx.x;
    int n = min(gcur[b], CAPD);
    size_t base = (size_t)b * CAPD;
    for (int i = t; i < n; i += 256) recs[i] = dreg[base + i];
    cnt[t] = 0;
    __syncthreads();
    for (int i = t; i < n; i += 256) atomicAdd(&cnt[recs[i].x >> 20], 1);
    __syncthreads();
    int my = cnt[t];
    sc[t] = my;
    __syncthreads();
    for (int off = 1; off < 256; off <<= 1) {
        int v = (t >= off) ? sc[t - off] : 0;
        __syncthreads();
        sc[t] += v;
        __syncthreads();
    }
    int ex = sc[t] - my;
    offs_s[t] = ex;
    int node = (b << RSH) + t;
    if (node < N) { colstart[node] = (int)(base + ex); colcnt[node] = my; }
    cnt[t] = 0;
    __syncthreads();
    for (int i = t; i < n; i += 256) {
        int2 rc = recs[i];
        int cl = rc.x >> 20;
        int r = rc.x & 0xFFFFF;
        float coef = __int_as_float(rc.y) * dis[r] * dis[(b << RSH) + cl];
        int pos = offs_s[cl] + atomicAdd(&cnt[cl], 1);
        dreg[base + pos] = make_int2(r, __float_as_int(coef));
    }
}

// ---- fused gather + MFMA head, wave-synchronous; dual-batch fused gather loop ----
__global__ __launch_bounds__(256, 4)
void ghead_kernel(const int2* __restrict__ recs,
                  const int* __restrict__ colstart, const int* __restrict__ colcnt,
                  const float* __restrict__ dis,
                  const unsigned short* __restrict__ xbf,
                  const float* __restrict__ W1, const float* __restrict__ b1,
                  const float* __restrict__ W2, const float* __restrict__ b2,
                  unsigned short* __restrict__ hb, float* __restrict__ outp, int N) {
    __shared__ __align__(16) unsigned short atile[4][16][72];
    __shared__ __align__(16) unsigned short htile[4][16][72];
    int tid = threadIdx.x;
    int l = tid & 63, w = tid >> 6;
    int col = l & 15, kg = l >> 4;
    int q = l >> 3, d8 = l & 7;          // gather: node sub-slot / dim-block

    short8 w1f[4][2];
    #pragma unroll
    for (int ct = 0; ct < 4; ++ct)
        #pragma unroll
        for (int kt = 0; kt < 2; ++kt) {
            const float* src = W1 + (16 * ct + col) * DD + 32 * kt + 8 * kg;
            short8 f;
            #pragma unroll
            for (int j = 0; j < 8; ++j) f[j] = (short)f2bf(src[j]);
            w1f[ct][kt] = f;
        }
    short8 w2f[2];
    #pragma unroll
    for (int kt = 0; kt < 2; ++kt) {
        short8 f;
        #pragma unroll
        for (int j = 0; j < 8; ++j)
            f[j] = (col < OUTD) ? (short)f2bf(W2[col * HH + 32 * kt + 8 * kg + j]) : (short)0;
        w2f[kt] = f;
    }
    float b1v[4];
    #pragma unroll
    for (int ct = 0; ct < 4; ++ct) b1v[ct] = b1[16 * ct + col];
    float b2v = (col < OUTD) ? b2[col] : 0.f;

    int ngrp = (N + 15) >> 4;
    for (int grp = blockIdx.x * 4 + w; grp < ngrp; grp += gridDim.x * 4) {
        int base = grp * 16;
        int node0 = base + q;
        int node1 = base + 8 + q;
        bool v0 = node0 < N, v1 = node1 < N;
        float s0 = v0 ? dis[node0] : 0.f;
        float s1 = v1 ? dis[node1] : 0.f;
        uint4 xv0 = v0 ? *(const uint4*)(xbf + (size_t)node0 * DD + 8 * d8) : make_uint4(0,0,0,0);
        uint4 xv1 = v1 ? *(const uint4*)(xbf + (size_t)node1 * DD + 8 * d8) : make_uint4(0,0,0,0);
        float s20 = s0 * s0, s21 = s1 * s1;
        float a0 = s20 * bflo(xv0.x), a1 = s20 * bfhi(xv0.x);
        float a2 = s20 * bflo(xv0.y), a3 = s20 * bfhi(xv0.y);
        float a4 = s20 * bflo(xv0.z), a5 = s20 * bfhi(xv0.z);
        float a6 = s20 * bflo(xv0.w), a7 = s20 * bfhi(xv0.w);
        float e0 = s21 * bflo(xv1.x), e1 = s21 * bfhi(xv1.x);
        float e2 = s21 * bflo(xv1.y), e3 = s21 * bfhi(xv1.y);
        float e4 = s21 * bflo(xv1.z), e5 = s21 * bfhi(xv1.z);
        float e6 = s21 * bflo(xv1.w), e7 = s21 * bfhi(xv1.w);
        int cnt0 = v0 ? colcnt[node0] : 0;
        int cnt1 = v1 ? colcnt[node1] : 0;
        const int2* p0 = recs + (v0 ? colstart[node0] : 0);
        const int2* p1 = recs + (v1 ? colstart[node1] : 0);
        int m = max(cnt0, cnt1);
        int c0m = max(cnt0 - 1, 0), c1m = max(cnt1 - 1, 0);
        for (int k = 0; k < m; k += 2) {
            // 4 independent rec loads + 4 independent x-row loads in flight
            int i00 = min(k, c0m),     i01 = min(k + 1, c0m);
            int i10 = min(k, c1m),     i11 = min(k + 1, c1m);
            int2 r00 = p0[i00], r01 = p0[i01];
            int2 r10 = p1[i10], r11 = p1[i11];
            uint4 q00 = *(const uint4*)(xbf + (size_t)r00.x * DD + 8 * d8);
            uint4 q01 = *(const uint4*)(xbf + (size_t)r01.x * DD + 8 * d8);
            uint4 q10 = *(const uint4*)(xbf + (size_t)r10.x * DD + 8 * d8);
            uint4 q11 = *(const uint4*)(xbf + (size_t)r11.x * DD + 8 * d8);
            float c00 = (k     < cnt0) ? __int_as_float(r00.y) : 0.f;
            float c01 = (k + 1 < cnt0) ? __int_as_float(r01.y) : 0.f;
            float c10 = (k     < cnt1) ? __int_as_float(r10.y) : 0.f;
            float c11 = (k + 1 < cnt1) ? __int_as_float(r11.y) : 0.f;
            a0 += c00 * bflo(q00.x); a1 += c00 * bfhi(q00.x);
            a2 += c00 * bflo(q00.y); a3 += c00 * bfhi(q00.y);
            a4 += c00 * bflo(q00.z); a5 += c00 * bfhi(q00.z);
            a6 += c00 * bflo(q00.w); a7 += c00 * bfhi(q00.w);
            a0 += c01 * bflo(q01.x); a1 += c01 * bfhi(q01.x);
            a2 += c01 * bflo(q01.y); a3 += c01 * bfhi(q01.y);
            a4 += c01 * bflo(q01.z); a5 += c01 * bfhi(q01.z);
            a6 += c01 * bflo(q01.w); a7 += c01 * bfhi(q01.w);
            e0 += c10 * bflo(q10.x); e1 += c10 * bfhi(q10.x);
            e2 += c10 * bflo(q10.y); e3 += c10 * bfhi(q10.y);
            e4 += c10 * bflo(q10.z); e5 += c10 * bfhi(q10.z);
            e6 += c10 * bflo(q10.w); e7 += c10 * bfhi(q10.w);
            e0 += c11 * bflo(q11.x); e1 += c11 * bfhi(q11.x);
            e2 += c11 * bflo(q11.y); e3 += c11 * bfhi(q11.y);
            e4 += c11 * bflo(q11.z); e5 += c11 * bfhi(q11.z);
            e6 += c11 * bflo(q11.w); e7 += c11 * bfhi(q11.w);
        }
        {
            uint4 o;
            o.x = (unsigned)f2bf(a0) | ((unsigned)f2bf(a1) << 16);
            o.y = (unsigned)f2bf(a2) | ((unsigned)f2bf(a3) << 16);
            o.z = (unsigned)f2bf(a4) | ((unsigned)f2bf(a5) << 16);
            o.w = (unsigned)f2bf(a6) | ((unsigned)f2bf(a7) << 16);
            *(uint4*)&atile[w][q][8 * d8] = o;
            uint4 o2;
            o2.x = (unsigned)f2bf(e0) | ((unsigned)f2bf(e1) << 16);
            o2.y = (unsigned)f2bf(e2) | ((unsigned)f2bf(e3) << 16);
            o2.z = (unsigned)f2bf(e4) | ((unsigned)f2bf(e5) << 16);
            o2.w = (unsigned)f2bf(e6) | ((unsigned)f2bf(e7) << 16);
            *(uint4*)&atile[w][8 + q][8 * d8] = o2;
        }
        // ---- GEMM1 from wave-private LDS tile (wave-sync, no barrier) ----
        short8 af[2];
        #pragma unroll
        for (int kt = 0; kt < 2; ++kt)
            af[kt] = *(const short8*)&atile[w][col][32 * kt + 8 * kg];
        #pragma unroll
        for (int ct = 0; ct < 4; ++ct) {
            f32x4 acc = {0.f, 0.f, 0.f, 0.f};
            acc = __builtin_amdgcn_mfma_f32_16x16x32_bf16(af[0], w1f[ct][0], acc, 0, 0, 0);
            acc = __builtin_amdgcn_mfma_f32_16x16x32_bf16(af[1], w1f[ct][1], acc, 0, 0, 0);
            #pragma unroll
            for (int jr = 0; jr < 4; ++jr) {
                float v = acc[jr] + b1v[ct];
                float ez = __expf(2.f * v);
                htile[w][4 * kg + jr][16 * ct + col] = f2bf((ez - 1.f) / (ez + 1.f));
            }
        }
        // ---- hb store (coalesced uint4 per lane) ----
        #pragma unroll
        for (int it = 0; it < 2; ++it) {
            int node = base + it * 8 + q;
            if (node < N)
                *(uint4*)(hb + (size_t)node * HH + 8 * d8) =
                    *(const uint4*)&htile[w][it * 8 + q][8 * d8];
        }
        // ---- GEMM2 (out head) ----
        short8 hf[2];
        #pragma unroll
        for (int kt = 0; kt < 2; ++kt)
            hf[kt] = *(const short8*)&htile[w][col][32 * kt + 8 * kg];
        f32x4 acc2 = {0.f, 0.f, 0.f, 0.f};
        acc2 = __builtin_amdgcn_mfma_f32_16x16x32_bf16(hf[0], w2f[0], acc2, 0, 0, 0);
        acc2 = __builtin_amdgcn_mfma_f32_16x16x32_bf16(hf[1], w2f[1], acc2, 0, 0, 0);
        if (col < OUTD) {
            #pragma unroll
            for (int jr = 0; jr < 4; ++jr) {
                int node = base + 4 * kg + jr;
                if (node < N) outp[(size_t)node * OUTD + col] = sigmoidf_(acc2[jr] + b2v);
            }
        }
    }
}

// ---- mean-pool partials: unconditional writes, no atomics, no zero-init ----
__global__ void pool_kernel(const unsigned short* __restrict__ hb,
                            const int* __restrict__ batch, int N,
                            float* __restrict__ pp) {
    int g = blockIdx.x / PSPLIT;
    int part = blockIdx.x % PSPLIT;
    int s = lbound_(batch, N, g);
    int e = lbound_(batch, N, g + 1);
    int tid = threadIdx.x;
    int hc = tid & 63, nl = tid >> 6;
    float sum = 0.0f;
    for (int n = s + part * 4 + nl; n < e; n += PSPLIT * 4)
        sum += bf2f(hb[(size_t)n * HH + hc]);
    __shared__ float red[4][HH];
    red[nl][hc] = sum;
    __syncthreads();
    if (nl == 0)
        pp[((size_t)g * PSPLIT + part) * HH + hc] =
            red[0][hc] + red[1][hc] + red[2][hc] + red[3][hc];
}

// ---- optimal head: sum partials, dot with Wopt ----
__global__ void optimal_kernel(const float* __restrict__ pp,
                               const int* __restrict__ batch, int N,
                               const float* __restrict__ Wopt,
                               const float* __restrict__ bopt,
                               float* __restrict__ out2) {
    int g = blockIdx.x;
    int d = threadIdx.x;
    int s = lbound_(batch, N, g);
    int e = lbound_(batch, N, g + 1);
    float c = fmaxf((float)(e - s), 1.0f);
    float acc = 0.f;
    #pragma unroll
    for (int part = 0; part < PSPLIT; ++part)
        acc += pp[((size_t)g * PSPLIT + part) * HH + d];
    float v = acc / c * Wopt[d];
    #pragma unroll
    for (int off = 32; off > 0; off >>= 1) v += __shfl_down(v, off);
    if (d == 0) out2[g] = 1.0f / (1.0f + __expf(-(v + bopt[0])));
}

extern "C" void kernel_launch(void* const* d_in, const int* in_sizes, int n_in,
                              void* d_out, int out_size, void* d_ws, size_t ws_size,
                              hipStream_t stream) {
    const float* x     = (const float*)d_in[0];
    const int*   ei    = (const int*)d_in[1];
    const float* ea    = (const float*)d_in[2];
    const int*   batch = (const int*)d_in[3];
    const float* W1    = (const float*)d_in[4];
    const float* b1    = (const float*)d_in[5];
    const float* W2    = (const float*)d_in[6];
    const float* b2    = (const float*)d_in[7];
    const float* Wopt  = (const float*)d_in[8];
    const float* bopt  = (const float*)d_in[9];

    int N = in_sizes[0] / DD;
    int E = in_sizes[2];
    int nbins = (N + 255) >> 8;        // 391 for N=100000 (<= NB=512)

    float* out  = (float*)d_out;               // [N, 8]
    float* out2 = out + (size_t)N * OUTD;      // [G]

    // ws: dis[N] | colstart[N] | colcnt[N] | pp[NG*PSPLIT*HH] | gcur[NB] | scur[NB] |
    //     dreg[nbins*CAPD]int2 | sreg[nbins*CAPD]u8 | xbf[N*64]u16 | hb[N*64]u16
    char* p = (char*)d_ws;
    float* dis      = (float*)p;  p += (size_t)N * 4;
    int*   colstart = (int*)p;    p += (size_t)N * 4;
    int*   colcnt   = (int*)p;    p += (size_t)N * 4;
    float* pp       = (float*)p;  p += (size_t)NG * PSPLIT * HH * 4;
    int*   gcur     = (int*)p;    p += (size_t)NB * 4;
    int*   scur     = (int*)p;    p += (size_t)NB * 4;
    uintptr_t up = (uintptr_t)p; up = (up + 15) & ~(uintptr_t)15; p = (char*)up;
    int2* dreg = (int2*)p;        p += (size_t)nbins * CAPD * 8;
    unsigned char* sreg = (unsigned char*)p; p += (size_t)nbins * CAPD;
    up = (uintptr_t)p; up = (up + 15) & ~(uintptr_t)15; p = (char*)up;
    unsigned short* xbf = (unsigned short*)p; p += (size_t)N * DD * 2;
    unsigned short* hb  = (unsigned short*)p;

    int n8 = N * DD / 8;
    int nbin = (E + BIN_CHUNK - 1) / BIN_CHUNK;
    int nxc = (n8 + BT - 1) / BT;

    init_kernel<<<1, 2 * NB, 0, stream>>>(gcur);   // gcur+scur adjacent
    bin_xcvt_kernel<<<nbin + nxc, BT, 0, stream>>>(ei, ea, gcur, scur, dreg, sreg,
                                                   E, nbin,
                                                   (const float4*)x, (uint4*)xbf, n8);
    deg_kernel<<<nbins, 256, 0, stream>>>(sreg, scur, dis, N);
    csr_kernel<<<nbins, 256, 0, stream>>>(dreg, gcur, dis, colstart, colcnt, N);

    int ngrp = (N + 15) / 16;
    ghead_kernel<<<(ngrp + 3) / 4, 256, 0, stream>>>(dreg, colstart, colcnt, dis, xbf,
                                                     W1, b1, W2, b2, hb, out, N);

    pool_kernel<<<NG * PSPLIT, 256, 0, stream>>>(hb, batch, N, pp);
    optimal_kernel<<<NG, 64, 0, stream>>>(pp, batch, N, Wopt, bopt, out2);
}